// Round 11
// baseline (437.996 us; speedup 1.0000x reference)
//
#include <hip/hip_runtime.h>
#include <hip/hip_bf16.h>
#include <math.h>

// ---- problem constants ----
#define NH   16
#define HD   128
#define HID  2048
#define NKV  6144      // 3*NH*HD
#define B_   2
#define S_   2048
#define NC   32        // S/CHUNK
#define CHUNK_ 64
#define GROUPS_ 8

typedef __bf16 bf16_t;
typedef bf16_t bf16x8 __attribute__((ext_vector_type(8)));
typedef float  f32x4  __attribute__((ext_vector_type(4)));

__device__ __forceinline__ float b2f(unsigned int u) {
    union { unsigned int u; float f; } c; c.u = (u & 0xffffu) << 16; return c.f;
}
__device__ __forceinline__ unsigned int f2b(float f) {
    union { float f; unsigned int u; } c; c.f = f;
    unsigned int u = c.u;
    return (u + 0x7fffu + ((u >> 16) & 1u)) >> 16;
}

#define GLOAD_LDS16(gp, lp) __builtin_amdgcn_global_load_lds(                     \
    (const __attribute__((address_space(1))) void*)(gp),                          \
    (__attribute__((address_space(3))) void*)(lp), 16, 0, 0)

#define BAR()     asm volatile("s_barrier" ::: "memory")
#define VMCNT0()  asm volatile("s_waitcnt vmcnt(0)" ::: "memory")

// ======= merged prep: hidden fp32->bf16 (blocks 0..4095) + all weight =======
// transposes in 64x64 tiles (blocks 4096..9215). One launch; full-line writes.
// Transpose: 256B coalesced fp32 reads, 128B bf16 row writes, pad-65 LDS
// (conflict-free column reads). Same f2b on same floats -> bit-identical.
__global__ __launch_bounds__(256) void prep(const float* __restrict__ hidden,
                                            const float* __restrict__ wq,
                                            const float* __restrict__ wg,
                                            const float* __restrict__ wd,
                                            unsigned short* __restrict__ hbf,
                                            unsigned short* __restrict__ outQG,
                                            unsigned short* __restrict__ outD)
{
    int bid = blockIdx.x;
    int tid = threadIdx.x;
    if (bid < 4096) {
        // ---- cvt path: 8 elems/thread ----
        int i = bid * 256 + tid;
        const float4* p = (const float4*)hidden + (size_t)i * 2;
        float4 a = p[0], b = p[1];
        uint4 o;
        o.x = f2b(a.x) | (f2b(a.y) << 16);
        o.y = f2b(a.z) | (f2b(a.w) << 16);
        o.z = f2b(b.x) | (f2b(b.y) << 16);
        o.w = f2b(b.z) | (f2b(b.w) << 16);
        ((uint4*)hbf)[i] = o;
        return;
    }
    // ---- transpose path: 64x64 tile ----
    __shared__ float tile[64][65];
    int tb = bid - 4096;              // 0..5119
    int bx = tb & 127;                // wait: 160 n-tiles -> use %160
    int by;
    bx = tb % 160;                    // combined n-tile (96 wq + 32 wg + 32 wd)
    by = tb / 160;                    // k-tile (2048/64)
    int lx = tid & 63, ly = tid >> 6; // 64 lanes/row, 4 rows/pass
    const float* in; int Ndim, c0, rowbase; unsigned short* outp;
    if (bx < 96)       { in = wq; Ndim = NKV; c0 = bx * 64;         outp = outQG; rowbase = bx * 64; }
    else if (bx < 128) { in = wg; Ndim = HID; c0 = (bx - 96) * 64;  outp = outQG; rowbase = bx * 64; }
    else               { in = wd; Ndim = HID; c0 = (bx - 128) * 64; outp = outD;  rowbase = (bx - 128) * 64; }
    int r0 = by * 64;
    #pragma unroll
    for (int r = 0; r < 16; ++r)
        tile[ly + r * 4][lx] = in[(size_t)(r0 + ly + r * 4) * Ndim + c0 + lx];
    __syncthreads();
    #pragma unroll
    for (int r = 0; r < 16; ++r)
        outp[(size_t)(rowbase + ly + r * 4) * HID + r0 + lx] = (unsigned short)f2b(tile[lx][ly + r * 4]);
}

// ================= 256x256 barrier-light GEMM (qkv+gate fused) ===============
// Round-3 proven (117us / MfmaUtil ~52): depth-1 prefetch, ONE vmcnt(0)+
// barrier per K-tile, A+B LDS-staged, st_16x32 swizzle, XCD 8x8 map. FROZEN.
__device__ __forceinline__ void ld_fr4(bf16x8 (&d)[4][2], const bf16_t* b, int s0, int ri) {
    #pragma unroll
    for (int i = 0; i < 4; ++i)
        #pragma unroll
        for (int k = 0; k < 2; ++k)
            d[i][k] = *(const bf16x8*)(b + (((s0 + i) * 2 + k) << 9) + ri);
}
__device__ __forceinline__ void ld_fr2(bf16x8 (&d)[2][2], const bf16_t* b, int s0, int ri) {
    #pragma unroll
    for (int i = 0; i < 2; ++i)
        #pragma unroll
        for (int k = 0; k < 2; ++k)
            d[i][k] = *(const bf16x8*)(b + (((s0 + i) * 2 + k) << 9) + ri);
}
__device__ __forceinline__ void mfma_quad(f32x4 (&a)[4][2], const bf16x8 (&af)[4][2],
                                          const bf16x8 (&bv)[2][2]) {
    #pragma unroll
    for (int mt = 0; mt < 4; ++mt)
        #pragma unroll
        for (int nt = 0; nt < 2; ++nt)
            #pragma unroll
            for (int ks = 0; ks < 2; ++ks)
                a[mt][nt] = __builtin_amdgcn_mfma_f32_16x16x32_bf16(af[mt][ks], bv[nt][ks], a[mt][nt], 0, 0, 0);
}

__global__ __launch_bounds__(512, 2) void gemm_qg_256(const bf16_t* __restrict__ A,
                                                      const bf16_t* __restrict__ Bt,
                                                      unsigned short* __restrict__ Cq,
                                                      unsigned short* __restrict__ Cg)
{
    __shared__ bf16_t Asm[2][2][8192];   // [buf][half][128*64]
    __shared__ bf16_t Bsm[2][2][8192];
    const int K  = HID;       // 2048
    const int NT = K / 64;    // 32 K-tiles

    int tid  = threadIdx.x;
    int wave = tid >> 6, lane = tid & 63;
    int wm = wave >> 2, wn = wave & 3;            // 2 M-waves x 4 N-waves
    int l16 = lane & 15, quad = lane >> 4;
    int wm4 = wm * 4, wn2 = wn * 2;

    int bid = blockIdx.x;
    int xcd = bid & 7, idx = bid >> 3;
    int by  = (xcd >> 2) * 8 + (idx >> 3);        // 0..15
    int bx  = (xcd & 3) * 8 + (idx & 7);          // 0..31

    int rd_in = ((l16 << 5) | (quad << 3)) ^ (((l16 >> 3) & 1) << 4);
    int ch = lane ^ ((lane & 32) >> 4);
    int rr = ch >> 2;
    int cc = (ch & 3) * 8;

    const bf16_t* aSrc0 = A  + (size_t)(by * 256 +       wave * 16 + rr) * K + cc;
    const bf16_t* aSrc1 = A  + (size_t)(by * 256 + 128 + wave * 16 + rr) * K + cc;
    const bf16_t* bSrc0 = Bt + (size_t)(bx * 256 +       wave * 16 + rr) * K + cc;
    const bf16_t* bSrc1 = Bt + (size_t)(bx * 256 + 128 + wave * 16 + rr) * K + cc;

#define STAGE_A(h, t) do {                                                        \
        const bf16_t* _g = ((h) ? aSrc1 : aSrc0) + (size_t)(t) * 64;              \
        bf16_t* _l = &Asm[(t) & 1][(h)][wave * 1024 + lane * 8];                  \
        GLOAD_LDS16(_g,      _l);                                                 \
        GLOAD_LDS16(_g + 32, _l + 512); } while (0)
#define STAGE_B(h, t) do {                                                        \
        const bf16_t* _g = ((h) ? bSrc1 : bSrc0) + (size_t)(t) * 64;              \
        bf16_t* _l = &Bsm[(t) & 1][(h)][wave * 1024 + lane * 8];                  \
        GLOAD_LDS16(_g,      _l);                                                 \
        GLOAD_LDS16(_g + 32, _l + 512); } while (0)

    f32x4 acc[2][2][4][2];
    #pragma unroll
    for (int a0 = 0; a0 < 2; ++a0)
        #pragma unroll
        for (int a1 = 0; a1 < 2; ++a1)
            #pragma unroll
            for (int a2 = 0; a2 < 4; ++a2)
                #pragma unroll
                for (int a3 = 0; a3 < 2; ++a3) { f32x4 z = {0.f,0.f,0.f,0.f}; acc[a0][a1][a2][a3] = z; }

    STAGE_A(0, 0); STAGE_B(0, 0); STAGE_A(1, 0); STAGE_B(1, 0);
    VMCNT0();
    BAR();

    #pragma unroll 2
    for (int t = 0; t < NT - 1; ++t) {
        const int buf = t & 1;
        STAGE_A(0, t + 1); STAGE_B(0, t + 1); STAGE_A(1, t + 1); STAGE_B(1, t + 1);
        {
            bf16x8 afA[4][2], afB[4][2], bf0[2][2], bf1[2][2];
            ld_fr4(afA, &Asm[buf][0][0], wm4, rd_in);
            ld_fr2(bf0, &Bsm[buf][0][0], wn2, rd_in);
            mfma_quad(acc[0][0], afA, bf0);
            ld_fr2(bf1, &Bsm[buf][1][0], wn2, rd_in);
            mfma_quad(acc[0][1], afA, bf1);
            ld_fr4(afB, &Asm[buf][1][0], wm4, rd_in);
            mfma_quad(acc[1][1], afB, bf1);
            mfma_quad(acc[1][0], afB, bf0);
        }
        VMCNT0();
        BAR();
    }
    {
        const int buf = (NT - 1) & 1;
        bf16x8 afA[4][2], afB[4][2], bf0[2][2], bf1[2][2];
        ld_fr4(afA, &Asm[buf][0][0], wm4, rd_in);
        ld_fr2(bf0, &Bsm[buf][0][0], wn2, rd_in);
        mfma_quad(acc[0][0], afA, bf0);
        ld_fr2(bf1, &Bsm[buf][1][0], wn2, rd_in);
        mfma_quad(acc[0][1], afA, bf1);
        ld_fr4(afB, &Asm[buf][1][0], wm4, rd_in);
        mfma_quad(acc[1][1], afB, bf1);
        mfma_quad(acc[1][0], afB, bf0);
    }
#undef STAGE_A
#undef STAGE_B

    unsigned short* Cc; int Nn, colbase;
    if (bx < 24) { Cc = Cq; Nn = NKV; colbase = bx * 256; }
    else         { Cc = Cg; Nn = HID; colbase = bx * 256 - NKV; }
    int row0 = by * 256 + wm * 64 + quad * 4;
    int col0 = colbase + wn * 32 + l16;
    #pragma unroll
    for (int mh = 0; mh < 2; ++mh)
        #pragma unroll
        for (int nh = 0; nh < 2; ++nh)
            #pragma unroll
            for (int mt = 0; mt < 4; ++mt)
                #pragma unroll
                for (int nt = 0; nt < 2; ++nt) {
                    int col = col0 + nh * 128 + nt * 16;
                    #pragma unroll
                    for (int r = 0; r < 4; ++r) {
                        int row = row0 + mh * 128 + mt * 16 + r;
                        Cc[(size_t)row * Nn + col] = (unsigned short)f2b(acc[mh][nh][mt][nt][r]);
                    }
                }
}

// ============ 128x128 barrier-light out-projection: C = A @ Bt^T, fp32 out ====
__global__ __launch_bounds__(256, 2) void gemm_out_128(const bf16_t* __restrict__ A,
                                                       const bf16_t* __restrict__ Bt,
                                                       float* __restrict__ C)
{
    __shared__ bf16_t As[2][4096];
    __shared__ bf16_t Bs[2][4096];
    const int K  = HID;
    const int NT = K / 32;

    int tid  = threadIdx.x;
    int wave = tid >> 6, lane = tid & 63;
    int wm2 = wave >> 1, wn2 = wave & 1;
    int l16 = lane & 15, quad = lane >> 4;
    int w2 = wave * 2;

    int bid = blockIdx.x;
    int xcd = bid & 7, idx = bid >> 3;
    int by  = (xcd >> 1) * 8 + (idx >> 3);
    int bx  = (xcd & 1) * 8 + (idx & 7);

    int rd_in = ((l16 << 5) | (quad << 3)) ^ (((l16 >> 3) & 1) << 4);
    int ch = lane ^ ((lane & 32) >> 4);
    int rr = ch >> 2;
    int cc = (ch & 3) * 8;

    const bf16_t* aSrc = A  + (size_t)(by * 128 + w2 * 16 + rr) * K + cc;
    const bf16_t* bSrc = Bt + (size_t)(bx * 128 + w2 * 16 + rr) * K + cc;

#define OSTAGE(t) do {                                                            \
        const int nb_ = (t) & 1;                                                  \
        const bf16_t* _ga = aSrc + (size_t)(t) * 32;                              \
        const bf16_t* _gb = bSrc + (size_t)(t) * 32;                              \
        GLOAD_LDS16(_ga,                  &As[nb_][w2 * 512 + lane * 8]);         \
        GLOAD_LDS16(_ga + (size_t)16 * K, &As[nb_][w2 * 512 + 512 + lane * 8]);   \
        GLOAD_LDS16(_gb,                  &Bs[nb_][w2 * 512 + lane * 8]);         \
        GLOAD_LDS16(_gb + (size_t)16 * K, &Bs[nb_][w2 * 512 + 512 + lane * 8]); } while (0)

    f32x4 acc[4][4];
    #pragma unroll
    for (int i = 0; i < 4; ++i)
        #pragma unroll
        for (int j = 0; j < 4; ++j) { f32x4 z = {0.f,0.f,0.f,0.f}; acc[i][j] = z; }

#define OCOMP(t) do {                                                             \
        const int b_ = (t) & 1;                                                   \
        bf16x8 af_[4], bf_[4];                                                    \
        _Pragma("unroll")                                                         \
        for (int i = 0; i < 4; ++i)                                               \
            af_[i] = *(const bf16x8*)(&As[b_][((wm2 * 4 + i) << 9) + rd_in]);     \
        _Pragma("unroll")                                                         \
        for (int j = 0; j < 4; ++j)                                               \
            bf_[j] = *(const bf16x8*)(&Bs[b_][((wn2 * 4 + j) << 9) + rd_in]);     \
        _Pragma("unroll")                                                         \
        for (int i = 0; i < 4; ++i)                                               \
            _Pragma("unroll")                                                     \
            for (int j = 0; j < 4; ++j)                                           \
                acc[i][j] = __builtin_amdgcn_mfma_f32_16x16x32_bf16(af_[i], bf_[j], acc[i][j], 0, 0, 0); } while (0)

    OSTAGE(0);
    VMCNT0();
    BAR();
    #pragma unroll 2
    for (int t = 0; t < NT - 1; ++t) {
        OSTAGE(t + 1);
        OCOMP(t);
        VMCNT0();
        BAR();
    }
    OCOMP(NT - 1);
#undef OSTAGE
#undef OCOMP

    #pragma unroll
    for (int i = 0; i < 4; ++i)
        #pragma unroll
        for (int j = 0; j < 4; ++j) {
            int col = bx * 128 + wn2 * 64 + j * 16 + l16;
            #pragma unroll
            for (int r = 0; r < 4; ++r) {
                int row = by * 128 + wm2 * 64 + i * 16 + quad * 4 + r;
                C[(size_t)row * HID + col] = acc[i][j][r];
            }
        }
}

// ------- q/k RMSNorm + partial RoPE. LDS sincos table (32 angles/block) -------
__global__ __launch_bounds__(256) void norm_rope(unsigned short* __restrict__ qkv,
                                                 const int* __restrict__ positions,
                                                 const float* __restrict__ qw,
                                                 const float* __restrict__ kw)
{
    __shared__ float tcs[32], tsn[32];
    int bs = blockIdx.x;
    int s  = bs & (S_ - 1);
    int tid = threadIdx.x;
    int l16 = tid & 15;
    unsigned short* base = qkv + (size_t)bs * NKV;
    float pos = (float)positions[s];

    if (tid < 32) {
        float ang = pos * exp2f(-(float)tid * 0.4152410118609203f);
        tcs[tid] = cosf(ang);
        tsn[tid] = sinf(ang);
    }
    __syncthreads();

    #pragma unroll
    for (int p = 0; p < 2; ++p) {
        int rr = p * 16 + (tid >> 4);   // 0..31
        int qk = rr >> 4;
        int h  = rr & 15;
        unsigned short* row = base + qk * HID + h * HD;
        const float* w = qk ? kw : qw;
        uint4 v = *(const uint4*)(row + l16 * 8);
        float x[8];
        x[0] = b2f(v.x); x[1] = b2f(v.x >> 16);
        x[2] = b2f(v.y); x[3] = b2f(v.y >> 16);
        x[4] = b2f(v.z); x[5] = b2f(v.z >> 16);
        x[6] = b2f(v.w); x[7] = b2f(v.w >> 16);
        float ss = 0.f;
        #pragma unroll
        for (int t = 0; t < 8; ++t) ss += x[t] * x[t];
        ss += __shfl_xor(ss, 1); ss += __shfl_xor(ss, 2);
        ss += __shfl_xor(ss, 4); ss += __shfl_xor(ss, 8);
        float inv = rsqrtf(ss * (1.0f / 128.0f) + 1e-6f);
        float n[8];
        #pragma unroll
        for (int t = 0; t < 8; ++t) n[t] = x[t] * inv * w[l16 * 8 + t];
        float pr[8];
        #pragma unroll
        for (int t = 0; t < 8; ++t) pr[t] = __shfl_xor(n[t], 4);   // dims +-32
        if (l16 < 8) {
            #pragma unroll
            for (int t = 0; t < 8; ++t) {
                int dim = l16 * 8 + t;
                int i = dim & 31;
                float cs = tcs[i], sn = tsn[i];
                n[t] = (dim < 32) ? (n[t] * cs - pr[t] * sn) : (n[t] * cs + pr[t] * sn);
            }
        }
        uint4 o;
        o.x = f2b(n[0]) | (f2b(n[1]) << 16);
        o.y = f2b(n[2]) | (f2b(n[3]) << 16);
        o.z = f2b(n[4]) | (f2b(n[5]) << 16);
        o.w = f2b(n[6]) | (f2b(n[7]) << 16);
        *(uint4*)(row + l16 * 8) = o;
    }
}

// ============ pass 1: per-chunk KV outer product, frag-packed wbuf ============
__global__ __launch_bounds__(256) void chunk_kv(const unsigned short* __restrict__ qkv,
                                                unsigned short* __restrict__ wbuf)
{
    __shared__ unsigned short kt[128 * 72];   // kt[d][j]
    __shared__ unsigned short vt[128 * 72];   // vt[e][j] * kdec[j]
    __shared__ float kdec[64];
    int bi = blockIdx.x;
    int c = bi & 31, bh = bi >> 5, h = bh & 15, b = bh >> 4;
    int tid = threadIdx.x;
    float slope = -exp2f(-0.5f * (float)(h + 1)) * (1.0f + 1e-5f);

    if (tid < 64) kdec[tid] = expf(slope * (float)(63 - tid));
    __syncthreads();

    const unsigned short* kbase = qkv + ((size_t)(b * S_ + c * CHUNK_)) * NKV + HID + h * HD;
    const unsigned short* vbase = kbase + HID;

    for (int idx = tid; idx < 4096; idx += 256) {
        int j = idx >> 6, p = idx & 63;
        unsigned int ku = *(const unsigned int*)(kbase + (size_t)j * NKV + p * 2);
        kt[(2 * p) * 72 + j]     = (unsigned short)(ku & 0xffffu);
        kt[(2 * p + 1) * 72 + j] = (unsigned short)(ku >> 16);
        float kd = kdec[j];
        unsigned int vu = *(const unsigned int*)(vbase + (size_t)j * NKV + p * 2);
        vt[(2 * p) * 72 + j]     = (unsigned short)f2b(b2f(vu) * kd);
        vt[(2 * p + 1) * 72 + j] = (unsigned short)f2b(b2f(vu >> 16) * kd);
    }
    __syncthreads();

    int lane = tid & 63, wave = tid >> 6;
    int wm = (wave >> 1) * 64;     // e
    int wn = (wave & 1) * 64;      // d
    int l16 = lane & 15, quad = lane >> 4;

    f32x4 acc[4][4];
    #pragma unroll
    for (int i = 0; i < 4; ++i)
        #pragma unroll
        for (int j = 0; j < 4; ++j) { f32x4 z = {0.f,0.f,0.f,0.f}; acc[i][j] = z; }

    #pragma unroll
    for (int ks = 0; ks < 64; ks += 32) {
        bf16x8 af[4], bf[4];
        #pragma unroll
        for (int t = 0; t < 4; ++t) {
            af[t] = *(const bf16x8*)((const bf16_t*)vt + (wm + t * 16 + l16) * 72 + ks + quad * 8);
            bf[t] = *(const bf16x8*)((const bf16_t*)kt + (wn + t * 16 + l16) * 72 + ks + quad * 8);
        }
        #pragma unroll
        for (int mt = 0; mt < 4; ++mt)
            #pragma unroll
            for (int nt = 0; nt < 4; ++nt)
                acc[mt][nt] = __builtin_amdgcn_mfma_f32_16x16x32_bf16(af[mt], bf[nt], acc[mt][nt], 0, 0, 0);
    }

    // frag-packed write
    unsigned short* wp = wbuf + ((size_t)bi << 14);
    #pragma unroll
    for (int mt = 0; mt < 4; ++mt)
        #pragma unroll
        for (int nt = 0; nt < 4; ++nt) {
            int cid = ((wave >> 1) * 4 + mt) * 4 + (wave & 1) * 2 + (nt >> 1);
            int pos = ((nt & 1) * 2 + (l16 >> 3)) * 128 + (l16 & 7);
            #pragma unroll
            for (int r = 0; r < 4; ++r) {
                int e15 = quad * 4 + r;
                wp[cid * 512 + pos + e15 * 8] = (unsigned short)f2b(acc[mt][nt][r]);
            }
        }
}

// ============ pass 2: state scan, frag-packed, 512 blocks (2/CU for TLP) ======
__global__ __launch_bounds__(256) void state_scan(const unsigned short* __restrict__ wbuf,
                                                  const float* __restrict__ rs0,
                                                  unsigned short* __restrict__ stbuf)
{
    int bi = blockIdx.x;
    int s = bi & 15, bh = bi >> 4, h = bh & 15, b = bh >> 4;
    int tid = threadIdx.x;
    float slope = -exp2f(-0.5f * (float)(h + 1)) * (1.0f + 1e-5f);
    float lam = expf(slope * 64.0f);

    int T    = s * 256 + tid;          // 0..4095
    int cid  = T >> 7;
    int pos  = (T * 4) & 511;
    int a    = pos >> 7;               // (d>>3)&3
    int e15  = (pos >> 3) & 15;
    int d7   = pos & 7;                // 0 or 4
    int e    = (cid >> 2) * 16 + e15;
    int d0   = (cid & 3) * 32 + a * 8 + d7;

    float S[4];
    const float* rp = rs0 + ((size_t)(b * NH + h)) * HD * HD + e;
    #pragma unroll
    for (int t = 0; t < 4; ++t) S[t] = rp[(size_t)(d0 + t) * HD];

    size_t base = (((size_t)bh * NC) << 14) + (size_t)T * 4;
    uint2 w0 = *(const uint2*)(wbuf + base);
    uint2 w1 = *(const uint2*)(wbuf + base + (1 << 14));
    for (int c = 0; c < NC; ++c) {
        uint2 o;
        o.x = f2b(S[0]) | (f2b(S[1]) << 16);
        o.y = f2b(S[2]) | (f2b(S[3]) << 16);
        *(uint2*)(stbuf + base) = o;
        uint2 w2 = w1;
        if (c + 2 < NC) w2 = *(const uint2*)(wbuf + base + (2 << 14));
        S[0] = S[0] * lam + b2f(w0.x); S[1] = S[1] * lam + b2f(w0.x >> 16);
        S[2] = S[2] * lam + b2f(w0.y); S[3] = S[3] * lam + b2f(w0.y >> 16);
        w0 = w1; w1 = w2;
        base += (1 << 14);
    }
}

// ============ pass 3: per-chunk output  O = (mask.QK^T)@V + qdec*(Q@S_prev)
__global__ __launch_bounds__(256) void chunk_out(const unsigned short* __restrict__ qkv,
                                                 const unsigned short* __restrict__ stbuf,
                                                 unsigned short* __restrict__ obuf)
{
    __shared__ unsigned short qs[64 * 136];   // q[i][d]
    __shared__ unsigned short kss[64 * 136];  // k[j][d]
    __shared__ unsigned short vt[128 * 72];   // v^T[e][j]
    __shared__ unsigned short sc[64 * 72];    // masked scores [i][j]
    __shared__ float decp[65], decm[64];

    int bi = blockIdx.x;
    int c = bi & 31, bh = bi >> 5, h = bh & 15, b = bh >> 4;
    int tid = threadIdx.x;
    float slope = -exp2f(-0.5f * (float)(h + 1)) * (1.0f + 1e-5f);

    int lane = tid & 63, wave = tid >> 6;
    int l16 = lane & 15, quad = lane >> 4;
    int wn3 = wave * 32;

    if (tid < 65)       decp[tid]      = expf(slope * (float)tid);
    else if (tid < 129) decm[tid - 65] = expf(-slope * (float)(tid - 65));

    // prefetch st B-frags (frag-packed: contiguous 1KB per wave per frag)
    const unsigned short* stp = stbuf + (((size_t)bh * NC + c) << 14);
    bf16x8 bsf[4][2];
    #pragma unroll
    for (int ksp4 = 0; ksp4 < 4; ++ksp4)
        #pragma unroll
        for (int nt = 0; nt < 2; ++nt)
            bsf[ksp4][nt] = *(const bf16x8*)((const bf16_t*)stp +
                (((wave * 2 + nt) * 4 + ksp4) << 9) + lane * 8);

    const unsigned short* qrow = qkv + ((size_t)(b * S_ + c * CHUNK_)) * NKV + h * HD;
    const unsigned short* krow = qrow + HID;
    // stage q and k (rows of 128, padded stride 136), coalesced uint4
    for (int idx = tid; idx < 1024; idx += 256) {
        int row = idx >> 4, c8 = (idx & 15) * 8;
        *(uint4*)(qs  + row * 136 + c8) = *(const uint4*)(qrow + (size_t)row * NKV + c8);
        *(uint4*)(kss + row * 136 + c8) = *(const uint4*)(krow + (size_t)row * NKV + c8);
    }
    // stage v transposed
    const unsigned short* vbase = qrow + 2 * HID;
    for (int idx = tid; idx < 4096; idx += 256) {
        int j = idx >> 6, p = idx & 63;
        unsigned int vu = *(const unsigned int*)(vbase + (size_t)j * NKV + p * 2);
        vt[(2 * p) * 72 + j]     = (unsigned short)(vu & 0xffffu);
        vt[(2 * p + 1) * 72 + j] = (unsigned short)(vu >> 16);
    }
    __syncthreads();

    // scores
    {
        f32x4 accS[4];
        #pragma unroll
        for (int t = 0; t < 4; ++t) { f32x4 z = {0.f,0.f,0.f,0.f}; accS[t] = z; }
        #pragma unroll
        for (int ksp = 0; ksp < 128; ksp += 32) {
            bf16x8 aq = *(const bf16x8*)((const bf16_t*)qs + (wave * 16 + l16) * 136 + ksp + quad * 8);
            #pragma unroll
            for (int nt = 0; nt < 4; ++nt) {
                bf16x8 bk = *(const bf16x8*)((const bf16_t*)kss + (nt * 16 + l16) * 136 + ksp + quad * 8);
                accS[nt] = __builtin_amdgcn_mfma_f32_16x16x32_bf16(aq, bk, accS[nt], 0, 0, 0);
            }
        }
        float ad[4];
        #pragma unroll
        for (int r = 0; r < 4; ++r) ad[r] = decp[wave * 16 + quad * 4 + r];
        #pragma unroll
        for (int nt = 0; nt < 4; ++nt) {
            int j = nt * 16 + l16;
            float bd = decm[j];
            #pragma unroll
            for (int r = 0; r < 4; ++r) {
                int i = wave * 16 + quad * 4 + r;
                float v = (i >= j) ? accS[nt][r] * ad[r] * bd : 0.0f;
                sc[i * 72 + j] = (unsigned short)f2b(v);
            }
        }
    }
    __syncthreads();

    f32x4 accI[4][2], accE[4][2];
    #pragma unroll
    for (int i = 0; i < 4; ++i)
        #pragma unroll
        for (int j = 0; j < 2; ++j) { f32x4 z = {0.f,0.f,0.f,0.f}; accI[i][j] = z; accE[i][j] = z; }

    // intra: K = 64 (j)
    #pragma unroll
    for (int ksp = 0; ksp < 64; ksp += 32) {
        bf16x8 as[4], bv[2];
        #pragma unroll
        for (int mt = 0; mt < 4; ++mt)
            as[mt] = *(const bf16x8*)((const bf16_t*)sc + (mt * 16 + l16) * 72 + ksp + quad * 8);
        #pragma unroll
        for (int nt = 0; nt < 2; ++nt)
            bv[nt] = *(const bf16x8*)((const bf16_t*)vt + (wn3 + nt * 16 + l16) * 72 + ksp + quad * 8);
        #pragma unroll
        for (int mt = 0; mt < 4; ++mt)
            #pragma unroll
            for (int nt = 0; nt < 2; ++nt)
                accI[mt][nt] = __builtin_amdgcn_mfma_f32_16x16x32_bf16(as[mt], bv[nt], accI[mt][nt], 0, 0, 0);
    }
    // inter: K = 128 (d)
    #pragma unroll
    for (int ksp4 = 0; ksp4 < 4; ++ksp4) {
        bf16x8 aq[4];
        #pragma unroll
        for (int mt = 0; mt < 4; ++mt)
            aq[mt] = *(const bf16x8*)((const bf16_t*)qs + (mt * 16 + l16) * 136 + ksp4 * 32 + quad * 8);
        #pragma unroll
        for (int mt = 0; mt < 4; ++mt)
            #pragma unroll
            for (int nt = 0; nt < 2; ++nt)
                accE[mt][nt] = __builtin_amdgcn_mfma_f32_16x16x32_bf16(aq[mt], bsf[ksp4][nt], accE[mt][nt], 0, 0, 0);
    }

    // epilogue
    #pragma unroll
    for (int mt = 0; mt < 4; ++mt) {
        #pragma unroll
        for (int r = 0; r < 4; ++r) {
            int i = mt * 16 + quad * 4 + r;
            float qd = decp[i + 1];
            int orow = b * S_ + c * CHUNK_ + i;
            #pragma unroll
            for (int nt = 0; nt < 2; ++nt) {
                int col = h * HD + wn3 + nt * 16 + l16;
                float o = accI[mt][nt][r] + qd * accE[mt][nt][r];
                obuf[(size_t)orow * 2048 + col] = (unsigned short)f2b(o);
            }
        }
    }
}

// ------- group RMSNorm + sigmoid gate, vectorized x8: 1 block per row --------
__global__ __launch_bounds__(256) void gnorm_gate(const unsigned short* __restrict__ o,
                                                  unsigned short* __restrict__ gate,
                                                  const float* __restrict__ gw)
{
    int row = blockIdx.x;
    int tid = threadIdx.x;
    size_t base8 = (size_t)row * 256 + tid;
    uint4 ov = ((const uint4*)o)[base8];
    uint4 gv = ((const uint4*)gate)[base8];
    float x[8];
    x[0] = b2f(ov.x); x[1] = b2f(ov.x >> 16);
    x[2] = b2f(ov.y); x[3] = b2f(ov.y >> 16);
    x[4] = b2f(ov.z); x[5] = b2f(ov.z >> 16);
    x[6] = b2f(ov.w); x[7] = b2f(ov.w >> 16);
    float ss = 0.f;
    #pragma unroll
    for (int t = 0; t < 8; ++t) ss += x[t] * x[t];
    ss += __shfl_xor(ss, 1); ss += __shfl_xor(ss, 2); ss += __shfl_xor(ss, 4);
    ss += __shfl_xor(ss, 8); ss += __shfl_xor(ss, 16);
    float inv = rsqrtf(ss * (1.0f / 256.0f) + 1e-6f);
    const float4* gwp = (const float4*)(gw + tid * 8);
    float4 w0 = gwp[0], w1 = gwp[1];
    float g[8];
    g[0] = b2f(gv.x); g[1] = b2f(gv.x >> 16);
    g[2] = b2f(gv.y); g[3] = b2f(gv.y >> 16);
    g[4] = b2f(gv.z); g[5] = b2f(gv.z >> 16);
    g[6] = b2f(gv.w); g[7] = b2f(gv.w >> 16);
    float wv[8] = {w0.x, w0.y, w0.z, w0.w, w1.x, w1.y, w1.z, w1.w};
    float r[8];
    #pragma unroll
    for (int t = 0; t < 8; ++t) {
        float sig = 1.0f / (1.0f + expf(-g[t]));
        r[t] = x[t] * inv * wv[t] * sig;
    }
    uint4 out;
    out.x = f2b(r[0]) | (f2b(r[1]) << 16);
    out.y = f2b(r[2]) | (f2b(r[3]) << 16);
    out.z = f2b(r[4]) | (f2b(r[5]) << 16);
    out.w = f2b(r[6]) | (f2b(r[7]) << 16);
    ((uint4*)gate)[base8] = out;
}

// ---------------- launch ----------------
extern "C" void kernel_launch(void* const* d_in, const int* in_sizes, int n_in,
                              void* d_out, int out_size, void* d_ws, size_t ws_size,
                              hipStream_t stream) {
    const int*   positions = (const int*)d_in[0];
    const float* hidden    = (const float*)d_in[1];
    const float* rstate    = (const float*)d_in[2];
    const float* w_qkv     = (const float*)d_in[3];
    const float* w_g       = (const float*)d_in[4];
    const float* w_dense   = (const float*)d_in[5];
    const float* q_norm_w  = (const float*)d_in[6];
    const float* k_norm_w  = (const float*)d_in[7];
    const float* g_norm_w  = (const float*)d_in[8];
    float* out = (float*)d_out;

    const int MR = B_ * S_;  // 4096

    // ---- ws layout (unchanged) ----
    char* w = (char*)d_ws;
    unsigned short* qkv  = (unsigned short*)w;            w += (size_t)MR * NKV * 2;     // 50.3 MB
    unsigned short* gbuf = (unsigned short*)w;            w += (size_t)MR * 2048 * 2;    // 16.8 MB
    unsigned short* wdT  = (unsigned short*)w;            w += (size_t)HID * HID * 2;    // 8.4 MB
    char* regionA = w;                                    w += (size_t)MR * HID * 2 + (size_t)8192 * HID * 2; // 50.3 MB
    char* regionB = w;                                    // 33.6 MB
    unsigned short* hbf   = (unsigned short*)regionA;                                 // 16.8 MB
    unsigned short* btQG  = (unsigned short*)(regionA + (size_t)MR * HID * 2);        // [8192][2048] 33.5 MB
    unsigned short* stbuf = (unsigned short*)regionA;     // 32 MB, after GEMMs
    unsigned short* wbuf  = (unsigned short*)regionB;     // 32 MB
    unsigned short* obuf  = (unsigned short*)regionB;     // 16.8 MB, after pass2

    // ---- prep: cvt (4096 blocks) + all weight transposes (5120 blocks) ----
    prep<<<dim3(4096 + 160 * 32), dim3(256), 0, stream>>>(
        hidden, w_qkv, w_g, w_dense, hbf, btQG, wdT);

    // ---- fused qkv+gate projection: 256^2 barrier-light (512 wg x 512 thr) ----
    gemm_qg_256<<<dim3(512), dim3(512), 0, stream>>>(
        (const bf16_t*)hbf, (const bf16_t*)btQG, qkv, gbuf);
    // ---- q/k norm + rope (dedicated pass, LDS trig table) ----
    norm_rope<<<dim3(B_ * S_), dim3(256), 0, stream>>>(qkv, positions, q_norm_w, k_norm_w);

    // ---- attention: 3-pass chunked scan (frag-packed wbuf/stbuf) ----
    chunk_kv<<<dim3(B_ * NH * NC), dim3(256), 0, stream>>>(qkv, wbuf);
    state_scan<<<dim3(B_ * NH * 16), dim3(256), 0, stream>>>(wbuf, rstate, stbuf);
    chunk_out<<<dim3(B_ * NH * NC), dim3(256), 0, stream>>>(qkv, stbuf, obuf);

    // ---- group norm + gate (vectorized, 1 block/row) ----
    gnorm_gate<<<dim3(MR), dim3(256), 0, stream>>>(obuf, gbuf, g_norm_w);
    // ---- output projection (fp32 out), barrier-light 128^2 ----
    gemm_out_128<<<dim3(512), dim3(256), 0, stream>>>(
        (const bf16_t*)gbuf, (const bf16_t*)wdT, out);
}

// Round 12
// 400.289 us; speedup vs baseline: 1.0942x; 1.0942x over previous
//
#include <hip/hip_runtime.h>
#include <hip/hip_bf16.h>
#include <math.h>

// ---- problem constants ----
#define NH   16
#define HD   128
#define HID  2048
#define NKV  6144      // 3*NH*HD
#define B_   2
#define S_   2048
#define NC   32        // S/CHUNK
#define CHUNK_ 64
#define GROUPS_ 8

typedef __bf16 bf16_t;
typedef bf16_t bf16x8 __attribute__((ext_vector_type(8)));
typedef float  f32x4  __attribute__((ext_vector_type(4)));

__device__ __forceinline__ float b2f(unsigned int u) {
    union { unsigned int u; float f; } c; c.u = (u & 0xffffu) << 16; return c.f;
}
__device__ __forceinline__ unsigned int f2b(float f) {
    union { float f; unsigned int u; } c; c.f = f;
    unsigned int u = c.u;
    return (u + 0x7fffu + ((u >> 16) & 1u)) >> 16;
}

#define GLOAD_LDS16(gp, lp) __builtin_amdgcn_global_load_lds(                     \
    (const __attribute__((address_space(1))) void*)(gp),                          \
    (__attribute__((address_space(3))) void*)(lp), 16, 0, 0)

#define BAR()     asm volatile("s_barrier" ::: "memory")
#define VMCNT0()  asm volatile("s_waitcnt vmcnt(0)" ::: "memory")

// ======= merged prep: hidden fp32->bf16 (blocks 0..4095) + all weight =======
// transposes in 64x64 tiles (blocks 4096..9215). One launch; full-line writes.
// Transpose: 256B coalesced fp32 reads, 128B bf16 row writes, pad-65 LDS
// (conflict-free column reads). Same f2b on same floats -> bit-identical.
__global__ __launch_bounds__(256) void prep(const float* __restrict__ hidden,
                                            const float* __restrict__ wq,
                                            const float* __restrict__ wg,
                                            const float* __restrict__ wd,
                                            unsigned short* __restrict__ hbf,
                                            unsigned short* __restrict__ outQG,
                                            unsigned short* __restrict__ outD)
{
    int bid = blockIdx.x;
    int tid = threadIdx.x;
    if (bid < 4096) {
        // ---- cvt path: 8 elems/thread ----
        int i = bid * 256 + tid;
        const float4* p = (const float4*)hidden + (size_t)i * 2;
        float4 a = p[0], b = p[1];
        uint4 o;
        o.x = f2b(a.x) | (f2b(a.y) << 16);
        o.y = f2b(a.z) | (f2b(a.w) << 16);
        o.z = f2b(b.x) | (f2b(b.y) << 16);
        o.w = f2b(b.z) | (f2b(b.w) << 16);
        ((uint4*)hbf)[i] = o;
        return;
    }
    // ---- transpose path: 64x64 tile ----
    __shared__ float tile[64][65];
    int tb = bid - 4096;              // 0..5119
    int bx = tb % 160;                // combined n-tile (96 wq + 32 wg + 32 wd)
    int by = tb / 160;                // k-tile (2048/64)
    int lx = tid & 63, ly = tid >> 6; // 64 lanes/row, 4 rows/pass
    const float* in; int Ndim, c0, rowbase; unsigned short* outp;
    if (bx < 96)       { in = wq; Ndim = NKV; c0 = bx * 64;         outp = outQG; rowbase = bx * 64; }
    else if (bx < 128) { in = wg; Ndim = HID; c0 = (bx - 96) * 64;  outp = outQG; rowbase = bx * 64; }
    else               { in = wd; Ndim = HID; c0 = (bx - 128) * 64; outp = outD;  rowbase = (bx - 128) * 64; }
    int r0 = by * 64;
    #pragma unroll
    for (int r = 0; r < 16; ++r)
        tile[ly + r * 4][lx] = in[(size_t)(r0 + ly + r * 4) * Ndim + c0 + lx];
    __syncthreads();
    #pragma unroll
    for (int r = 0; r < 16; ++r)
        outp[(size_t)(rowbase + ly + r * 4) * HID + r0 + lx] = (unsigned short)f2b(tile[lx][ly + r * 4]);
}

// ================= 256x256 barrier-light GEMM (qkv+gate fused) ===============
// Round-3 proven (117us / MfmaUtil ~52): depth-1 prefetch, ONE vmcnt(0)+
// barrier per K-tile, A+B LDS-staged, st_16x32 swizzle, XCD 8x8 map. FROZEN.
__device__ __forceinline__ void ld_fr4(bf16x8 (&d)[4][2], const bf16_t* b, int s0, int ri) {
    #pragma unroll
    for (int i = 0; i < 4; ++i)
        #pragma unroll
        for (int k = 0; k < 2; ++k)
            d[i][k] = *(const bf16x8*)(b + (((s0 + i) * 2 + k) << 9) + ri);
}
__device__ __forceinline__ void ld_fr2(bf16x8 (&d)[2][2], const bf16_t* b, int s0, int ri) {
    #pragma unroll
    for (int i = 0; i < 2; ++i)
        #pragma unroll
        for (int k = 0; k < 2; ++k)
            d[i][k] = *(const bf16x8*)(b + (((s0 + i) * 2 + k) << 9) + ri);
}
__device__ __forceinline__ void mfma_quad(f32x4 (&a)[4][2], const bf16x8 (&af)[4][2],
                                          const bf16x8 (&bv)[2][2]) {
    #pragma unroll
    for (int mt = 0; mt < 4; ++mt)
        #pragma unroll
        for (int nt = 0; nt < 2; ++nt)
            #pragma unroll
            for (int ks = 0; ks < 2; ++ks)
                a[mt][nt] = __builtin_amdgcn_mfma_f32_16x16x32_bf16(af[mt][ks], bv[nt][ks], a[mt][nt], 0, 0, 0);
}

__global__ __launch_bounds__(512, 2) void gemm_qg_256(const bf16_t* __restrict__ A,
                                                      const bf16_t* __restrict__ Bt,
                                                      unsigned short* __restrict__ Cq,
                                                      unsigned short* __restrict__ Cg)
{
    __shared__ bf16_t Asm[2][2][8192];   // [buf][half][128*64]
    __shared__ bf16_t Bsm[2][2][8192];
    const int K  = HID;       // 2048
    const int NT = K / 64;    // 32 K-tiles

    int tid  = threadIdx.x;
    int wave = tid >> 6, lane = tid & 63;
    int wm = wave >> 2, wn = wave & 3;            // 2 M-waves x 4 N-waves
    int l16 = lane & 15, quad = lane >> 4;
    int wm4 = wm * 4, wn2 = wn * 2;

    int bid = blockIdx.x;
    int xcd = bid & 7, idx = bid >> 3;
    int by  = (xcd >> 2) * 8 + (idx >> 3);        // 0..15
    int bx  = (xcd & 3) * 8 + (idx & 7);          // 0..31

    int rd_in = ((l16 << 5) | (quad << 3)) ^ (((l16 >> 3) & 1) << 4);
    int ch = lane ^ ((lane & 32) >> 4);
    int rr = ch >> 2;
    int cc = (ch & 3) * 8;

    const bf16_t* aSrc0 = A  + (size_t)(by * 256 +       wave * 16 + rr) * K + cc;
    const bf16_t* aSrc1 = A  + (size_t)(by * 256 + 128 + wave * 16 + rr) * K + cc;
    const bf16_t* bSrc0 = Bt + (size_t)(bx * 256 +       wave * 16 + rr) * K + cc;
    const bf16_t* bSrc1 = Bt + (size_t)(bx * 256 + 128 + wave * 16 + rr) * K + cc;

#define STAGE_A(h, t) do {                                                        \
        const bf16_t* _g = ((h) ? aSrc1 : aSrc0) + (size_t)(t) * 64;              \
        bf16_t* _l = &Asm[(t) & 1][(h)][wave * 1024 + lane * 8];                  \
        GLOAD_LDS16(_g,      _l);                                                 \
        GLOAD_LDS16(_g + 32, _l + 512); } while (0)
#define STAGE_B(h, t) do {                                                        \
        const bf16_t* _g = ((h) ? bSrc1 : bSrc0) + (size_t)(t) * 64;              \
        bf16_t* _l = &Bsm[(t) & 1][(h)][wave * 1024 + lane * 8];                  \
        GLOAD_LDS16(_g,      _l);                                                 \
        GLOAD_LDS16(_g + 32, _l + 512); } while (0)

    f32x4 acc[2][2][4][2];
    #pragma unroll
    for (int a0 = 0; a0 < 2; ++a0)
        #pragma unroll
        for (int a1 = 0; a1 < 2; ++a1)
            #pragma unroll
            for (int a2 = 0; a2 < 4; ++a2)
                #pragma unroll
                for (int a3 = 0; a3 < 2; ++a3) { f32x4 z = {0.f,0.f,0.f,0.f}; acc[a0][a1][a2][a3] = z; }

    STAGE_A(0, 0); STAGE_B(0, 0); STAGE_A(1, 0); STAGE_B(1, 0);
    VMCNT0();
    BAR();

    #pragma unroll 2
    for (int t = 0; t < NT - 1; ++t) {
        const int buf = t & 1;
        STAGE_A(0, t + 1); STAGE_B(0, t + 1); STAGE_A(1, t + 1); STAGE_B(1, t + 1);
        {
            bf16x8 afA[4][2], afB[4][2], bf0[2][2], bf1[2][2];
            ld_fr4(afA, &Asm[buf][0][0], wm4, rd_in);
            ld_fr2(bf0, &Bsm[buf][0][0], wn2, rd_in);
            mfma_quad(acc[0][0], afA, bf0);
            ld_fr2(bf1, &Bsm[buf][1][0], wn2, rd_in);
            mfma_quad(acc[0][1], afA, bf1);
            ld_fr4(afB, &Asm[buf][1][0], wm4, rd_in);
            mfma_quad(acc[1][1], afB, bf1);
            mfma_quad(acc[1][0], afB, bf0);
        }
        VMCNT0();
        BAR();
    }
    {
        const int buf = (NT - 1) & 1;
        bf16x8 afA[4][2], afB[4][2], bf0[2][2], bf1[2][2];
        ld_fr4(afA, &Asm[buf][0][0], wm4, rd_in);
        ld_fr2(bf0, &Bsm[buf][0][0], wn2, rd_in);
        mfma_quad(acc[0][0], afA, bf0);
        ld_fr2(bf1, &Bsm[buf][1][0], wn2, rd_in);
        mfma_quad(acc[0][1], afA, bf1);
        ld_fr4(afB, &Asm[buf][1][0], wm4, rd_in);
        mfma_quad(acc[1][1], afB, bf1);
        mfma_quad(acc[1][0], afB, bf0);
    }
#undef STAGE_A
#undef STAGE_B

    unsigned short* Cc; int Nn, colbase;
    if (bx < 24) { Cc = Cq; Nn = NKV; colbase = bx * 256; }
    else         { Cc = Cg; Nn = HID; colbase = bx * 256 - NKV; }
    int row0 = by * 256 + wm * 64 + quad * 4;
    int col0 = colbase + wn * 32 + l16;
    #pragma unroll
    for (int mh = 0; mh < 2; ++mh)
        #pragma unroll
        for (int nh = 0; nh < 2; ++nh)
            #pragma unroll
            for (int mt = 0; mt < 4; ++mt)
                #pragma unroll
                for (int nt = 0; nt < 2; ++nt) {
                    int col = col0 + nh * 128 + nt * 16;
                    #pragma unroll
                    for (int r = 0; r < 4; ++r) {
                        int row = row0 + mh * 128 + mt * 16 + r;
                        Cc[(size_t)row * Nn + col] = (unsigned short)f2b(acc[mh][nh][mt][nt][r]);
                    }
                }
}

// ============ 128x128 barrier-light out-projection: C = A @ Bt^T, fp32 out ====
__global__ __launch_bounds__(256, 2) void gemm_out_128(const bf16_t* __restrict__ A,
                                                       const bf16_t* __restrict__ Bt,
                                                       float* __restrict__ C)
{
    __shared__ bf16_t As[2][4096];
    __shared__ bf16_t Bs[2][4096];
    const int K  = HID;
    const int NT = K / 32;

    int tid  = threadIdx.x;
    int wave = tid >> 6, lane = tid & 63;
    int wm2 = wave >> 1, wn2 = wave & 1;
    int l16 = lane & 15, quad = lane >> 4;
    int w2 = wave * 2;

    int bid = blockIdx.x;
    int xcd = bid & 7, idx = bid >> 3;
    int by  = (xcd >> 1) * 8 + (idx >> 3);
    int bx  = (xcd & 1) * 8 + (idx & 7);

    int rd_in = ((l16 << 5) | (quad << 3)) ^ (((l16 >> 3) & 1) << 4);
    int ch = lane ^ ((lane & 32) >> 4);
    int rr = ch >> 2;
    int cc = (ch & 3) * 8;

    const bf16_t* aSrc = A  + (size_t)(by * 128 + w2 * 16 + rr) * K + cc;
    const bf16_t* bSrc = Bt + (size_t)(bx * 128 + w2 * 16 + rr) * K + cc;

#define OSTAGE(t) do {                                                            \
        const int nb_ = (t) & 1;                                                  \
        const bf16_t* _ga = aSrc + (size_t)(t) * 32;                              \
        const bf16_t* _gb = bSrc + (size_t)(t) * 32;                              \
        GLOAD_LDS16(_ga,                  &As[nb_][w2 * 512 + lane * 8]);         \
        GLOAD_LDS16(_ga + (size_t)16 * K, &As[nb_][w2 * 512 + 512 + lane * 8]);   \
        GLOAD_LDS16(_gb,                  &Bs[nb_][w2 * 512 + lane * 8]);         \
        GLOAD_LDS16(_gb + (size_t)16 * K, &Bs[nb_][w2 * 512 + 512 + lane * 8]); } while (0)

    f32x4 acc[4][4];
    #pragma unroll
    for (int i = 0; i < 4; ++i)
        #pragma unroll
        for (int j = 0; j < 4; ++j) { f32x4 z = {0.f,0.f,0.f,0.f}; acc[i][j] = z; }

#define OCOMP(t) do {                                                             \
        const int b_ = (t) & 1;                                                   \
        bf16x8 af_[4], bf_[4];                                                    \
        _Pragma("unroll")                                                         \
        for (int i = 0; i < 4; ++i)                                               \
            af_[i] = *(const bf16x8*)(&As[b_][((wm2 * 4 + i) << 9) + rd_in]);     \
        _Pragma("unroll")                                                         \
        for (int j = 0; j < 4; ++j)                                               \
            bf_[j] = *(const bf16x8*)(&Bs[b_][((wn2 * 4 + j) << 9) + rd_in]);     \
        _Pragma("unroll")                                                         \
        for (int i = 0; i < 4; ++i)                                               \
            _Pragma("unroll")                                                     \
            for (int j = 0; j < 4; ++j)                                           \
                acc[i][j] = __builtin_amdgcn_mfma_f32_16x16x32_bf16(af_[i], bf_[j], acc[i][j], 0, 0, 0); } while (0)

    OSTAGE(0);
    VMCNT0();
    BAR();
    #pragma unroll 2
    for (int t = 0; t < NT - 1; ++t) {
        OSTAGE(t + 1);
        OCOMP(t);
        VMCNT0();
        BAR();
    }
    OCOMP(NT - 1);
#undef OSTAGE
#undef OCOMP

    #pragma unroll
    for (int i = 0; i < 4; ++i)
        #pragma unroll
        for (int j = 0; j < 4; ++j) {
            int col = bx * 128 + wn2 * 64 + j * 16 + l16;
            #pragma unroll
            for (int r = 0; r < 4; ++r) {
                int row = by * 128 + wm2 * 64 + i * 16 + quad * 4 + r;
                C[(size_t)row * HID + col] = acc[i][j][r];
            }
        }
}

// ------- q/k RMSNorm + partial RoPE. LDS sincos table (32 angles/block) -------
__global__ __launch_bounds__(256) void norm_rope(unsigned short* __restrict__ qkv,
                                                 const int* __restrict__ positions,
                                                 const float* __restrict__ qw,
                                                 const float* __restrict__ kw)
{
    __shared__ float tcs[32], tsn[32];
    int bs = blockIdx.x;
    int s  = bs & (S_ - 1);
    int tid = threadIdx.x;
    int l16 = tid & 15;
    unsigned short* base = qkv + (size_t)bs * NKV;
    float pos = (float)positions[s];

    if (tid < 32) {
        float ang = pos * exp2f(-(float)tid * 0.4152410118609203f);
        tcs[tid] = cosf(ang);
        tsn[tid] = sinf(ang);
    }
    __syncthreads();

    #pragma unroll
    for (int p = 0; p < 2; ++p) {
        int rr = p * 16 + (tid >> 4);   // 0..31
        int qk = rr >> 4;
        int h  = rr & 15;
        unsigned short* row = base + qk * HID + h * HD;
        const float* w = qk ? kw : qw;
        uint4 v = *(const uint4*)(row + l16 * 8);
        float x[8];
        x[0] = b2f(v.x); x[1] = b2f(v.x >> 16);
        x[2] = b2f(v.y); x[3] = b2f(v.y >> 16);
        x[4] = b2f(v.z); x[5] = b2f(v.z >> 16);
        x[6] = b2f(v.w); x[7] = b2f(v.w >> 16);
        float ss = 0.f;
        #pragma unroll
        for (int t = 0; t < 8; ++t) ss += x[t] * x[t];
        ss += __shfl_xor(ss, 1); ss += __shfl_xor(ss, 2);
        ss += __shfl_xor(ss, 4); ss += __shfl_xor(ss, 8);
        float inv = rsqrtf(ss * (1.0f / 128.0f) + 1e-6f);
        float n[8];
        #pragma unroll
        for (int t = 0; t < 8; ++t) n[t] = x[t] * inv * w[l16 * 8 + t];
        float pr[8];
        #pragma unroll
        for (int t = 0; t < 8; ++t) pr[t] = __shfl_xor(n[t], 4);   // dims +-32
        if (l16 < 8) {
            #pragma unroll
            for (int t = 0; t < 8; ++t) {
                int dim = l16 * 8 + t;
                int i = dim & 31;
                float cs = tcs[i], sn = tsn[i];
                n[t] = (dim < 32) ? (n[t] * cs - pr[t] * sn) : (n[t] * cs + pr[t] * sn);
            }
        }
        uint4 o;
        o.x = f2b(n[0]) | (f2b(n[1]) << 16);
        o.y = f2b(n[2]) | (f2b(n[3]) << 16);
        o.z = f2b(n[4]) | (f2b(n[5]) << 16);
        o.w = f2b(n[6]) | (f2b(n[7]) << 16);
        *(uint4*)(row + l16 * 8) = o;
    }
}

// ============ pass 1: per-chunk KV outer product, frag-packed wbuf ============
__global__ __launch_bounds__(256) void chunk_kv(const unsigned short* __restrict__ qkv,
                                                unsigned short* __restrict__ wbuf)
{
    __shared__ unsigned short kt[128 * 72];   // kt[d][j]
    __shared__ unsigned short vt[128 * 72];   // vt[e][j] * kdec[j]
    __shared__ float kdec[64];
    int bi = blockIdx.x;
    int c = bi & 31, bh = bi >> 5, h = bh & 15, b = bh >> 4;
    int tid = threadIdx.x;
    float slope = -exp2f(-0.5f * (float)(h + 1)) * (1.0f + 1e-5f);

    if (tid < 64) kdec[tid] = expf(slope * (float)(63 - tid));
    __syncthreads();

    const unsigned short* kbase = qkv + ((size_t)(b * S_ + c * CHUNK_)) * NKV + HID + h * HD;
    const unsigned short* vbase = kbase + HID;

    for (int idx = tid; idx < 4096; idx += 256) {
        int j = idx >> 6, p = idx & 63;
        unsigned int ku = *(const unsigned int*)(kbase + (size_t)j * NKV + p * 2);
        kt[(2 * p) * 72 + j]     = (unsigned short)(ku & 0xffffu);
        kt[(2 * p + 1) * 72 + j] = (unsigned short)(ku >> 16);
        float kd = kdec[j];
        unsigned int vu = *(const unsigned int*)(vbase + (size_t)j * NKV + p * 2);
        vt[(2 * p) * 72 + j]     = (unsigned short)f2b(b2f(vu) * kd);
        vt[(2 * p + 1) * 72 + j] = (unsigned short)f2b(b2f(vu >> 16) * kd);
    }
    __syncthreads();

    int lane = tid & 63, wave = tid >> 6;
    int wm = (wave >> 1) * 64;     // e
    int wn = (wave & 1) * 64;      // d
    int l16 = lane & 15, quad = lane >> 4;

    f32x4 acc[4][4];
    #pragma unroll
    for (int i = 0; i < 4; ++i)
        #pragma unroll
        for (int j = 0; j < 4; ++j) { f32x4 z = {0.f,0.f,0.f,0.f}; acc[i][j] = z; }

    #pragma unroll
    for (int ks = 0; ks < 64; ks += 32) {
        bf16x8 af[4], bf[4];
        #pragma unroll
        for (int t = 0; t < 4; ++t) {
            af[t] = *(const bf16x8*)((const bf16_t*)vt + (wm + t * 16 + l16) * 72 + ks + quad * 8);
            bf[t] = *(const bf16x8*)((const bf16_t*)kt + (wn + t * 16 + l16) * 72 + ks + quad * 8);
        }
        #pragma unroll
        for (int mt = 0; mt < 4; ++mt)
            #pragma unroll
            for (int nt = 0; nt < 4; ++nt)
                acc[mt][nt] = __builtin_amdgcn_mfma_f32_16x16x32_bf16(af[mt], bf[nt], acc[mt][nt], 0, 0, 0);
    }

    // frag-packed write
    unsigned short* wp = wbuf + ((size_t)bi << 14);
    #pragma unroll
    for (int mt = 0; mt < 4; ++mt)
        #pragma unroll
        for (int nt = 0; nt < 4; ++nt) {
            int cid = ((wave >> 1) * 4 + mt) * 4 + (wave & 1) * 2 + (nt >> 1);
            int pos = ((nt & 1) * 2 + (l16 >> 3)) * 128 + (l16 & 7);
            #pragma unroll
            for (int r = 0; r < 4; ++r) {
                int e15 = quad * 4 + r;
                wp[cid * 512 + pos + e15 * 8] = (unsigned short)f2b(acc[mt][nt][r]);
            }
        }
}

// ============ pass 2: state scan, frag-packed, 512 blocks (2/CU for TLP) ======
__global__ __launch_bounds__(256) void state_scan(const unsigned short* __restrict__ wbuf,
                                                  const float* __restrict__ rs0,
                                                  unsigned short* __restrict__ stbuf)
{
    int bi = blockIdx.x;
    int s = bi & 15, bh = bi >> 4, h = bh & 15, b = bh >> 4;
    int tid = threadIdx.x;
    float slope = -exp2f(-0.5f * (float)(h + 1)) * (1.0f + 1e-5f);
    float lam = expf(slope * 64.0f);

    int T    = s * 256 + tid;          // 0..4095
    int cid  = T >> 7;
    int pos  = (T * 4) & 511;
    int a    = pos >> 7;               // (d>>3)&3
    int e15  = (pos >> 3) & 15;
    int d7   = pos & 7;                // 0 or 4
    int e    = (cid >> 2) * 16 + e15;
    int d0   = (cid & 3) * 32 + a * 8 + d7;

    float S[4];
    const float* rp = rs0 + ((size_t)(b * NH + h)) * HD * HD + e;
    #pragma unroll
    for (int t = 0; t < 4; ++t) S[t] = rp[(size_t)(d0 + t) * HD];

    size_t base = (((size_t)bh * NC) << 14) + (size_t)T * 4;
    uint2 w0 = *(const uint2*)(wbuf + base);
    uint2 w1 = *(const uint2*)(wbuf + base + (1 << 14));
    for (int c = 0; c < NC; ++c) {
        uint2 o;
        o.x = f2b(S[0]) | (f2b(S[1]) << 16);
        o.y = f2b(S[2]) | (f2b(S[3]) << 16);
        *(uint2*)(stbuf + base) = o;
        uint2 w2 = w1;
        if (c + 2 < NC) w2 = *(const uint2*)(wbuf + base + (2 << 14));
        S[0] = S[0] * lam + b2f(w0.x); S[1] = S[1] * lam + b2f(w0.x >> 16);
        S[2] = S[2] * lam + b2f(w0.y); S[3] = S[3] * lam + b2f(w0.y >> 16);
        w0 = w1; w1 = w2;
        base += (1 << 14);
    }
}

// ============ pass 3: per-chunk output  O = (mask.QK^T)@V + qdec*(Q@S_prev)
__global__ __launch_bounds__(256) void chunk_out(const unsigned short* __restrict__ qkv,
                                                 const unsigned short* __restrict__ stbuf,
                                                 unsigned short* __restrict__ obuf)
{
    __shared__ unsigned short qs[64 * 136];   // q[i][d]
    __shared__ unsigned short kss[64 * 136];  // k[j][d]
    __shared__ unsigned short vt[128 * 72];   // v^T[e][j]
    __shared__ unsigned short sc[64 * 72];    // masked scores [i][j]
    __shared__ float decp[65], decm[64];

    int bi = blockIdx.x;
    int c = bi & 31, bh = bi >> 5, h = bh & 15, b = bh >> 4;
    int tid = threadIdx.x;
    float slope = -exp2f(-0.5f * (float)(h + 1)) * (1.0f + 1e-5f);

    int lane = tid & 63, wave = tid >> 6;
    int l16 = lane & 15, quad = lane >> 4;
    int wn3 = wave * 32;

    if (tid < 65)       decp[tid]      = expf(slope * (float)tid);
    else if (tid < 129) decm[tid - 65] = expf(-slope * (float)(tid - 65));

    // prefetch st B-frags (frag-packed: contiguous 1KB per wave per frag)
    const unsigned short* stp = stbuf + (((size_t)bh * NC + c) << 14);
    bf16x8 bsf[4][2];
    #pragma unroll
    for (int ksp4 = 0; ksp4 < 4; ++ksp4)
        #pragma unroll
        for (int nt = 0; nt < 2; ++nt)
            bsf[ksp4][nt] = *(const bf16x8*)((const bf16_t*)stp +
                (((wave * 2 + nt) * 4 + ksp4) << 9) + lane * 8);

    const unsigned short* qrow = qkv + ((size_t)(b * S_ + c * CHUNK_)) * NKV + h * HD;
    const unsigned short* krow = qrow + HID;
    // stage q and k (rows of 128, padded stride 136), coalesced uint4
    for (int idx = tid; idx < 1024; idx += 256) {
        int row = idx >> 4, c8 = (idx & 15) * 8;
        *(uint4*)(qs  + row * 136 + c8) = *(const uint4*)(qrow + (size_t)row * NKV + c8);
        *(uint4*)(kss + row * 136 + c8) = *(const uint4*)(krow + (size_t)row * NKV + c8);
    }
    // stage v transposed
    const unsigned short* vbase = qrow + 2 * HID;
    for (int idx = tid; idx < 4096; idx += 256) {
        int j = idx >> 6, p = idx & 63;
        unsigned int vu = *(const unsigned int*)(vbase + (size_t)j * NKV + p * 2);
        vt[(2 * p) * 72 + j]     = (unsigned short)(vu & 0xffffu);
        vt[(2 * p + 1) * 72 + j] = (unsigned short)(vu >> 16);
    }
    __syncthreads();

    // scores
    {
        f32x4 accS[4];
        #pragma unroll
        for (int t = 0; t < 4; ++t) { f32x4 z = {0.f,0.f,0.f,0.f}; accS[t] = z; }
        #pragma unroll
        for (int ksp = 0; ksp < 128; ksp += 32) {
            bf16x8 aq = *(const bf16x8*)((const bf16_t*)qs + (wave * 16 + l16) * 136 + ksp + quad * 8);
            #pragma unroll
            for (int nt = 0; nt < 4; ++nt) {
                bf16x8 bk = *(const bf16x8*)((const bf16_t*)kss + (nt * 16 + l16) * 136 + ksp + quad * 8);
                accS[nt] = __builtin_amdgcn_mfma_f32_16x16x32_bf16(aq, bk, accS[nt], 0, 0, 0);
            }
        }
        float ad[4];
        #pragma unroll
        for (int r = 0; r < 4; ++r) ad[r] = decp[wave * 16 + quad * 4 + r];
        #pragma unroll
        for (int nt = 0; nt < 4; ++nt) {
            int j = nt * 16 + l16;
            float bd = decm[j];
            #pragma unroll
            for (int r = 0; r < 4; ++r) {
                int i = wave * 16 + quad * 4 + r;
                float v = (i >= j) ? accS[nt][r] * ad[r] * bd : 0.0f;
                sc[i * 72 + j] = (unsigned short)f2b(v);
            }
        }
    }
    __syncthreads();

    f32x4 accI[4][2], accE[4][2];
    #pragma unroll
    for (int i = 0; i < 4; ++i)
        #pragma unroll
        for (int j = 0; j < 2; ++j) { f32x4 z = {0.f,0.f,0.f,0.f}; accI[i][j] = z; accE[i][j] = z; }

    // intra: K = 64 (j)
    #pragma unroll
    for (int ksp = 0; ksp < 64; ksp += 32) {
        bf16x8 as[4], bv[2];
        #pragma unroll
        for (int mt = 0; mt < 4; ++mt)
            as[mt] = *(const bf16x8*)((const bf16_t*)sc + (mt * 16 + l16) * 72 + ksp + quad * 8);
        #pragma unroll
        for (int nt = 0; nt < 2; ++nt)
            bv[nt] = *(const bf16x8*)((const bf16_t*)vt + (wn3 + nt * 16 + l16) * 72 + ksp + quad * 8);
        #pragma unroll
        for (int mt = 0; mt < 4; ++mt)
            #pragma unroll
            for (int nt = 0; nt < 2; ++nt)
                accI[mt][nt] = __builtin_amdgcn_mfma_f32_16x16x32_bf16(as[mt], bv[nt], accI[mt][nt], 0, 0, 0);
    }
    // inter: K = 128 (d)
    #pragma unroll
    for (int ksp4 = 0; ksp4 < 4; ++ksp4) {
        bf16x8 aq[4];
        #pragma unroll
        for (int mt = 0; mt < 4; ++mt)
            aq[mt] = *(const bf16x8*)((const bf16_t*)qs + (mt * 16 + l16) * 136 + ksp4 * 32 + quad * 8);
        #pragma unroll
        for (int mt = 0; mt < 4; ++mt)
            #pragma unroll
            for (int nt = 0; nt < 2; ++nt)
                accE[mt][nt] = __builtin_amdgcn_mfma_f32_16x16x32_bf16(aq[mt], bsf[ksp4][nt], accE[mt][nt], 0, 0, 0);
    }

    // epilogue
    #pragma unroll
    for (int mt = 0; mt < 4; ++mt) {
        #pragma unroll
        for (int r = 0; r < 4; ++r) {
            int i = mt * 16 + quad * 4 + r;
            float qd = decp[i + 1];
            int orow = b * S_ + c * CHUNK_ + i;
            #pragma unroll
            for (int nt = 0; nt < 2; ++nt) {
                int col = h * HD + wn3 + nt * 16 + l16;
                float o = accI[mt][nt][r] + qd * accE[mt][nt][r];
                obuf[(size_t)orow * 2048 + col] = (unsigned short)f2b(o);
            }
        }
    }
}

// ------- group RMSNorm + sigmoid gate, vectorized x8: 1 block per row --------
__global__ __launch_bounds__(256) void gnorm_gate(const unsigned short* __restrict__ o,
                                                  unsigned short* __restrict__ gate,
                                                  const float* __restrict__ gw)
{
    int row = blockIdx.x;
    int tid = threadIdx.x;
    size_t base8 = (size_t)row * 256 + tid;
    uint4 ov = ((const uint4*)o)[base8];
    uint4 gv = ((const uint4*)gate)[base8];
    float x[8];
    x[0] = b2f(ov.x); x[1] = b2f(ov.x >> 16);
    x[2] = b2f(ov.y); x[3] = b2f(ov.y >> 16);
    x[4] = b2f(ov.z); x[5] = b2f(ov.z >> 16);
    x[6] = b2f(ov.w); x[7] = b2f(ov.w >> 16);
    float ss = 0.f;
    #pragma unroll
    for (int t = 0; t < 8; ++t) ss += x[t] * x[t];
    ss += __shfl_xor(ss, 1); ss += __shfl_xor(ss, 2); ss += __shfl_xor(ss, 4);
    ss += __shfl_xor(ss, 8); ss += __shfl_xor(ss, 16);
    float inv = rsqrtf(ss * (1.0f / 256.0f) + 1e-6f);
    const float4* gwp = (const float4*)(gw + tid * 8);
    float4 w0 = gwp[0], w1 = gwp[1];
    float g[8];
    g[0] = b2f(gv.x); g[1] = b2f(gv.x >> 16);
    g[2] = b2f(gv.y); g[3] = b2f(gv.y >> 16);
    g[4] = b2f(gv.z); g[5] = b2f(gv.z >> 16);
    g[6] = b2f(gv.w); g[7] = b2f(gv.w >> 16);
    float wv[8] = {w0.x, w0.y, w0.z, w0.w, w1.x, w1.y, w1.z, w1.w};
    float r[8];
    #pragma unroll
    for (int t = 0; t < 8; ++t) {
        float sig = 1.0f / (1.0f + expf(-g[t]));
        r[t] = x[t] * inv * wv[t] * sig;
    }
    uint4 out;
    out.x = f2b(r[0]) | (f2b(r[1]) << 16);
    out.y = f2b(r[2]) | (f2b(r[3]) << 16);
    out.z = f2b(r[4]) | (f2b(r[5]) << 16);
    out.w = f2b(r[6]) | (f2b(r[7]) << 16);
    ((uint4*)gate)[base8] = out;
}

// ---------------- launch ----------------
extern "C" void kernel_launch(void* const* d_in, const int* in_sizes, int n_in,
                              void* d_out, int out_size, void* d_ws, size_t ws_size,
                              hipStream_t stream) {
    const int*   positions = (const int*)d_in[0];
    const float* hidden    = (const float*)d_in[1];
    const float* rstate    = (const float*)d_in[2];
    const float* w_qkv     = (const float*)d_in[3];
    const float* w_g       = (const float*)d_in[4];
    const float* w_dense   = (const float*)d_in[5];
    const float* q_norm_w  = (const float*)d_in[6];
    const float* k_norm_w  = (const float*)d_in[7];
    const float* g_norm_w  = (const float*)d_in[8];
    float* out = (float*)d_out;

    const int MR = B_ * S_;  // 4096

    // ---- ws layout (unchanged) ----
    char* w = (char*)d_ws;
    unsigned short* qkv  = (unsigned short*)w;            w += (size_t)MR * NKV * 2;     // 50.3 MB
    unsigned short* gbuf = (unsigned short*)w;            w += (size_t)MR * 2048 * 2;    // 16.8 MB
    unsigned short* wdT  = (unsigned short*)w;            w += (size_t)HID * HID * 2;    // 8.4 MB
    char* regionA = w;                                    w += (size_t)MR * HID * 2 + (size_t)8192 * HID * 2; // 50.3 MB
    char* regionB = w;                                    // 33.6 MB
    unsigned short* hbf   = (unsigned short*)regionA;                                 // 16.8 MB
    unsigned short* btQG  = (unsigned short*)(regionA + (size_t)MR * HID * 2);        // [8192][2048] 33.5 MB
    unsigned short* stbuf = (unsigned short*)regionA;     // 32 MB, after GEMMs
    unsigned short* wbuf  = (unsigned short*)regionB;     // 32 MB
    unsigned short* obuf  = (unsigned short*)regionB;     // 16.8 MB, after pass2

    // ---- prep: cvt (4096 blocks) + all weight transposes (5120 blocks) ----
    prep<<<dim3(4096 + 160 * 32), dim3(256), 0, stream>>>(
        hidden, w_qkv, w_g, w_dense, hbf, btQG, wdT);

    // ---- fused qkv+gate projection: 256^2 barrier-light (512 wg x 512 thr) ----
    gemm_qg_256<<<dim3(512), dim3(512), 0, stream>>>(
        (const bf16_t*)hbf, (const bf16_t*)btQG, qkv, gbuf);
    // ---- q/k norm + rope (dedicated pass, LDS trig table) ----
    norm_rope<<<dim3(B_ * S_), dim3(256), 0, stream>>>(qkv, positions, q_norm_w, k_norm_w);

    // ---- attention: 3-pass chunked scan (frag-packed wbuf/stbuf) ----
    chunk_kv<<<dim3(B_ * NH * NC), dim3(256), 0, stream>>>(qkv, wbuf);
    state_scan<<<dim3(B_ * NH * 16), dim3(256), 0, stream>>>(wbuf, rstate, stbuf);
    chunk_out<<<dim3(B_ * NH * NC), dim3(256), 0, stream>>>(qkv, stbuf, obuf);

    // ---- group norm + gate (vectorized, 1 block/row) ----
    gnorm_gate<<<dim3(MR), dim3(256), 0, stream>>>(obuf, gbuf, g_norm_w);
    // ---- output projection (fp32 out), barrier-light 128^2 ----
    gemm_out_128<<<dim3(512), dim3(256), 0, stream>>>(
        (const bf16_t*)gbuf, (const bf16_t*)wdT, out);
}

// Round 13
// 390.526 us; speedup vs baseline: 1.1216x; 1.0250x over previous
//
#include <hip/hip_runtime.h>
#include <hip/hip_bf16.h>
#include <math.h>

// ---- problem constants ----
#define NH   16
#define HD   128
#define HID  2048
#define NKV  6144      // 3*NH*HD
#define B_   2
#define S_   2048
#define NC   32        // S/CHUNK
#define CHUNK_ 64
#define GROUPS_ 8

typedef __bf16 bf16_t;
typedef bf16_t bf16x8 __attribute__((ext_vector_type(8)));
typedef float  f32x4  __attribute__((ext_vector_type(4)));

__device__ __forceinline__ float b2f(unsigned int u) {
    union { unsigned int u; float f; } c; c.u = (u & 0xffffu) << 16; return c.f;
}
__device__ __forceinline__ unsigned int f2b(float f) {
    union { float f; unsigned int u; } c; c.f = f;
    unsigned int u = c.u;
    return (u + 0x7fffu + ((u >> 16) & 1u)) >> 16;
}

#define GLOAD_LDS16(gp, lp) __builtin_amdgcn_global_load_lds(                     \
    (const __attribute__((address_space(1))) void*)(gp),                          \
    (__attribute__((address_space(3))) void*)(lp), 16, 0, 0)

#define BAR()     asm volatile("s_barrier" ::: "memory")
#define VMCNT0()  asm volatile("s_waitcnt vmcnt(0)" ::: "memory")

// ---------------- fp32 -> bf16 elementwise (8 elems/thread) ----------------
__global__ __launch_bounds__(256) void cvt_bf16(const float* __restrict__ in,
                                                unsigned short* __restrict__ out, int n8)
{
    int i = blockIdx.x * 256 + threadIdx.x;
    if (i >= n8) return;
    const float4* p = (const float4*)in + (size_t)i * 2;
    float4 a = p[0], b = p[1];
    uint4 o;
    o.x = f2b(a.x) | (f2b(a.y) << 16);
    o.y = f2b(a.z) | (f2b(a.w) << 16);
    o.z = f2b(b.x) | (f2b(b.y) << 16);
    o.w = f2b(b.z) | (f2b(b.w) << 16);
    ((uint4*)out)[i] = o;
}

// ---- combined w_qkv + w_g + w_dense transpose (single launch, 32x32 tiles) ----
// bx<192: w_qkv -> btQG rows [0,6144); bx<256: w_g -> btQG rows [6144,8192);
// bx>=256: w_dense -> wdT rows [0,2048). All outputs row-major [N][K=2048] bf16.
__global__ __launch_bounds__(256) void transpose_qgd(const float* __restrict__ wq,
                                                     const float* __restrict__ wg,
                                                     const float* __restrict__ wd,
                                                     unsigned short* __restrict__ outQG,
                                                     unsigned short* __restrict__ outD)
{
    __shared__ float tile[32][33];
    int bx = blockIdx.x % 320;        // combined n-tile
    int by = blockIdx.x / 320;        // k-tile (2048/32)
    int lx = threadIdx.x & 31, ly = threadIdx.x >> 5;
    const float* in; int Ndim, c0, rowbase; unsigned short* outp;
    if (bx < 192)      { in = wq; Ndim = NKV; c0 = bx * 32;         outp = outQG; rowbase = bx * 32; }
    else if (bx < 256) { in = wg; Ndim = HID; c0 = (bx - 192) * 32; outp = outQG; rowbase = bx * 32; }
    else               { in = wd; Ndim = HID; c0 = (bx - 256) * 32; outp = outD;  rowbase = (bx - 256) * 32; }
    int r0 = by * 32;
    #pragma unroll
    for (int r = 0; r < 4; ++r)
        tile[ly + r * 8][lx] = in[(size_t)(r0 + ly + r * 8) * Ndim + c0 + lx];
    __syncthreads();
    #pragma unroll
    for (int r = 0; r < 4; ++r)
        outp[(size_t)(rowbase + ly + r * 8) * HID + r0 + lx] = (unsigned short)f2b(tile[lx][ly + r * 8]);
}

// ================= 256x256 barrier-light GEMM (qkv+gate fused) ===============
// Round-3 proven (117us / MfmaUtil ~52): depth-1 prefetch, ONE vmcnt(0)+
// barrier per K-tile, A+B LDS-staged, st_16x32 swizzle, XCD 8x8 map. FROZEN.
__device__ __forceinline__ void ld_fr4(bf16x8 (&d)[4][2], const bf16_t* b, int s0, int ri) {
    #pragma unroll
    for (int i = 0; i < 4; ++i)
        #pragma unroll
        for (int k = 0; k < 2; ++k)
            d[i][k] = *(const bf16x8*)(b + (((s0 + i) * 2 + k) << 9) + ri);
}
__device__ __forceinline__ void ld_fr2(bf16x8 (&d)[2][2], const bf16_t* b, int s0, int ri) {
    #pragma unroll
    for (int i = 0; i < 2; ++i)
        #pragma unroll
        for (int k = 0; k < 2; ++k)
            d[i][k] = *(const bf16x8*)(b + (((s0 + i) * 2 + k) << 9) + ri);
}
__device__ __forceinline__ void mfma_quad(f32x4 (&a)[4][2], const bf16x8 (&af)[4][2],
                                          const bf16x8 (&bv)[2][2]) {
    #pragma unroll
    for (int mt = 0; mt < 4; ++mt)
        #pragma unroll
        for (int nt = 0; nt < 2; ++nt)
            #pragma unroll
            for (int ks = 0; ks < 2; ++ks)
                a[mt][nt] = __builtin_amdgcn_mfma_f32_16x16x32_bf16(af[mt][ks], bv[nt][ks], a[mt][nt], 0, 0, 0);
}

__global__ __launch_bounds__(512, 2) void gemm_qg_256(const bf16_t* __restrict__ A,
                                                      const bf16_t* __restrict__ Bt,
                                                      unsigned short* __restrict__ Cq,
                                                      unsigned short* __restrict__ Cg)
{
    __shared__ bf16_t Asm[2][2][8192];   // [buf][half][128*64]
    __shared__ bf16_t Bsm[2][2][8192];
    const int K  = HID;       // 2048
    const int NT = K / 64;    // 32 K-tiles

    int tid  = threadIdx.x;
    int wave = tid >> 6, lane = tid & 63;
    int wm = wave >> 2, wn = wave & 3;            // 2 M-waves x 4 N-waves
    int l16 = lane & 15, quad = lane >> 4;
    int wm4 = wm * 4, wn2 = wn * 2;

    int bid = blockIdx.x;
    int xcd = bid & 7, idx = bid >> 3;
    int by  = (xcd >> 2) * 8 + (idx >> 3);        // 0..15
    int bx  = (xcd & 3) * 8 + (idx & 7);          // 0..31

    int rd_in = ((l16 << 5) | (quad << 3)) ^ (((l16 >> 3) & 1) << 4);
    int ch = lane ^ ((lane & 32) >> 4);
    int rr = ch >> 2;
    int cc = (ch & 3) * 8;

    const bf16_t* aSrc0 = A  + (size_t)(by * 256 +       wave * 16 + rr) * K + cc;
    const bf16_t* aSrc1 = A  + (size_t)(by * 256 + 128 + wave * 16 + rr) * K + cc;
    const bf16_t* bSrc0 = Bt + (size_t)(bx * 256 +       wave * 16 + rr) * K + cc;
    const bf16_t* bSrc1 = Bt + (size_t)(bx * 256 + 128 + wave * 16 + rr) * K + cc;

#define STAGE_A(h, t) do {                                                        \
        const bf16_t* _g = ((h) ? aSrc1 : aSrc0) + (size_t)(t) * 64;              \
        bf16_t* _l = &Asm[(t) & 1][(h)][wave * 1024 + lane * 8];                  \
        GLOAD_LDS16(_g,      _l);                                                 \
        GLOAD_LDS16(_g + 32, _l + 512); } while (0)
#define STAGE_B(h, t) do {                                                        \
        const bf16_t* _g = ((h) ? bSrc1 : bSrc0) + (size_t)(t) * 64;              \
        bf16_t* _l = &Bsm[(t) & 1][(h)][wave * 1024 + lane * 8];                  \
        GLOAD_LDS16(_g,      _l);                                                 \
        GLOAD_LDS16(_g + 32, _l + 512); } while (0)

    f32x4 acc[2][2][4][2];
    #pragma unroll
    for (int a0 = 0; a0 < 2; ++a0)
        #pragma unroll
        for (int a1 = 0; a1 < 2; ++a1)
            #pragma unroll
            for (int a2 = 0; a2 < 4; ++a2)
                #pragma unroll
                for (int a3 = 0; a3 < 2; ++a3) { f32x4 z = {0.f,0.f,0.f,0.f}; acc[a0][a1][a2][a3] = z; }

    STAGE_A(0, 0); STAGE_B(0, 0); STAGE_A(1, 0); STAGE_B(1, 0);
    VMCNT0();
    BAR();

    #pragma unroll 2
    for (int t = 0; t < NT - 1; ++t) {
        const int buf = t & 1;
        STAGE_A(0, t + 1); STAGE_B(0, t + 1); STAGE_A(1, t + 1); STAGE_B(1, t + 1);
        {
            bf16x8 afA[4][2], afB[4][2], bf0[2][2], bf1[2][2];
            ld_fr4(afA, &Asm[buf][0][0], wm4, rd_in);
            ld_fr2(bf0, &Bsm[buf][0][0], wn2, rd_in);
            mfma_quad(acc[0][0], afA, bf0);
            ld_fr2(bf1, &Bsm[buf][1][0], wn2, rd_in);
            mfma_quad(acc[0][1], afA, bf1);
            ld_fr4(afB, &Asm[buf][1][0], wm4, rd_in);
            mfma_quad(acc[1][1], afB, bf1);
            mfma_quad(acc[1][0], afB, bf0);
        }
        VMCNT0();
        BAR();
    }
    {
        const int buf = (NT - 1) & 1;
        bf16x8 afA[4][2], afB[4][2], bf0[2][2], bf1[2][2];
        ld_fr4(afA, &Asm[buf][0][0], wm4, rd_in);
        ld_fr2(bf0, &Bsm[buf][0][0], wn2, rd_in);
        mfma_quad(acc[0][0], afA, bf0);
        ld_fr2(bf1, &Bsm[buf][1][0], wn2, rd_in);
        mfma_quad(acc[0][1], afA, bf1);
        ld_fr4(afB, &Asm[buf][1][0], wm4, rd_in);
        mfma_quad(acc[1][1], afB, bf1);
        mfma_quad(acc[1][0], afB, bf0);
    }
#undef STAGE_A
#undef STAGE_B

    unsigned short* Cc; int Nn, colbase;
    if (bx < 24) { Cc = Cq; Nn = NKV; colbase = bx * 256; }
    else         { Cc = Cg; Nn = HID; colbase = bx * 256 - NKV; }
    int row0 = by * 256 + wm * 64 + quad * 4;
    int col0 = colbase + wn * 32 + l16;
    #pragma unroll
    for (int mh = 0; mh < 2; ++mh)
        #pragma unroll
        for (int nh = 0; nh < 2; ++nh)
            #pragma unroll
            for (int mt = 0; mt < 4; ++mt)
                #pragma unroll
                for (int nt = 0; nt < 2; ++nt) {
                    int col = col0 + nh * 128 + nt * 16;
                    #pragma unroll
                    for (int r = 0; r < 4; ++r) {
                        int row = row0 + mh * 128 + mt * 16 + r;
                        Cc[(size_t)row * Nn + col] = (unsigned short)f2b(acc[mh][nh][mt][nt][r]);
                    }
                }
}

// ============ 128x128 barrier-light out-projection: C = A @ Bt^T, fp32 out ====
__global__ __launch_bounds__(256, 2) void gemm_out_128(const bf16_t* __restrict__ A,
                                                       const bf16_t* __restrict__ Bt,
                                                       float* __restrict__ C)
{
    __shared__ bf16_t As[2][4096];
    __shared__ bf16_t Bs[2][4096];
    const int K  = HID;
    const int NT = K / 32;

    int tid  = threadIdx.x;
    int wave = tid >> 6, lane = tid & 63;
    int wm2 = wave >> 1, wn2 = wave & 1;
    int l16 = lane & 15, quad = lane >> 4;
    int w2 = wave * 2;

    int bid = blockIdx.x;
    int xcd = bid & 7, idx = bid >> 3;
    int by  = (xcd >> 1) * 8 + (idx >> 3);
    int bx  = (xcd & 1) * 8 + (idx & 7);

    int rd_in = ((l16 << 5) | (quad << 3)) ^ (((l16 >> 3) & 1) << 4);
    int ch = lane ^ ((lane & 32) >> 4);
    int rr = ch >> 2;
    int cc = (ch & 3) * 8;

    const bf16_t* aSrc = A  + (size_t)(by * 128 + w2 * 16 + rr) * K + cc;
    const bf16_t* bSrc = Bt + (size_t)(bx * 128 + w2 * 16 + rr) * K + cc;

#define OSTAGE(t) do {                                                            \
        const int nb_ = (t) & 1;                                                  \
        const bf16_t* _ga = aSrc + (size_t)(t) * 32;                              \
        const bf16_t* _gb = bSrc + (size_t)(t) * 32;                              \
        GLOAD_LDS16(_ga,                  &As[nb_][w2 * 512 + lane * 8]);         \
        GLOAD_LDS16(_ga + (size_t)16 * K, &As[nb_][w2 * 512 + 512 + lane * 8]);   \
        GLOAD_LDS16(_gb,                  &Bs[nb_][w2 * 512 + lane * 8]);         \
        GLOAD_LDS16(_gb + (size_t)16 * K, &Bs[nb_][w2 * 512 + 512 + lane * 8]); } while (0)

    f32x4 acc[4][4];
    #pragma unroll
    for (int i = 0; i < 4; ++i)
        #pragma unroll
        for (int j = 0; j < 4; ++j) { f32x4 z = {0.f,0.f,0.f,0.f}; acc[i][j] = z; }

#define OCOMP(t) do {                                                             \
        const int b_ = (t) & 1;                                                   \
        bf16x8 af_[4], bf_[4];                                                    \
        _Pragma("unroll")                                                         \
        for (int i = 0; i < 4; ++i)                                               \
            af_[i] = *(const bf16x8*)(&As[b_][((wm2 * 4 + i) << 9) + rd_in]);     \
        _Pragma("unroll")                                                         \
        for (int j = 0; j < 4; ++j)                                               \
            bf_[j] = *(const bf16x8*)(&Bs[b_][((wn2 * 4 + j) << 9) + rd_in]);     \
        _Pragma("unroll")                                                         \
        for (int i = 0; i < 4; ++i)                                               \
            _Pragma("unroll")                                                     \
            for (int j = 0; j < 4; ++j)                                           \
                acc[i][j] = __builtin_amdgcn_mfma_f32_16x16x32_bf16(af_[i], bf_[j], acc[i][j], 0, 0, 0); } while (0)

    OSTAGE(0);
    VMCNT0();
    BAR();
    #pragma unroll 2
    for (int t = 0; t < NT - 1; ++t) {
        OSTAGE(t + 1);
        OCOMP(t);
        VMCNT0();
        BAR();
    }
    OCOMP(NT - 1);
#undef OSTAGE
#undef OCOMP

    #pragma unroll
    for (int i = 0; i < 4; ++i)
        #pragma unroll
        for (int j = 0; j < 4; ++j) {
            int col = bx * 128 + wn2 * 64 + j * 16 + l16;
            #pragma unroll
            for (int r = 0; r < 4; ++r) {
                int row = by * 128 + wm2 * 64 + i * 16 + quad * 4 + r;
                C[(size_t)row * HID + col] = acc[i][j][r];
            }
        }
}

// ------- q/k RMSNorm + partial RoPE. LDS sincos table (32 angles/block) -------
__global__ __launch_bounds__(256) void norm_rope(unsigned short* __restrict__ qkv,
                                                 const int* __restrict__ positions,
                                                 const float* __restrict__ qw,
                                                 const float* __restrict__ kw)
{
    __shared__ float tcs[32], tsn[32];
    int bs = blockIdx.x;
    int s  = bs & (S_ - 1);
    int tid = threadIdx.x;
    int l16 = tid & 15;
    unsigned short* base = qkv + (size_t)bs * NKV;
    float pos = (float)positions[s];

    if (tid < 32) {
        float ang = pos * exp2f(-(float)tid * 0.4152410118609203f);
        tcs[tid] = cosf(ang);
        tsn[tid] = sinf(ang);
    }
    __syncthreads();

    #pragma unroll
    for (int p = 0; p < 2; ++p) {
        int rr = p * 16 + (tid >> 4);   // 0..31
        int qk = rr >> 4;
        int h  = rr & 15;
        unsigned short* row = base + qk * HID + h * HD;
        const float* w = qk ? kw : qw;
        uint4 v = *(const uint4*)(row + l16 * 8);
        float x[8];
        x[0] = b2f(v.x); x[1] = b2f(v.x >> 16);
        x[2] = b2f(v.y); x[3] = b2f(v.y >> 16);
        x[4] = b2f(v.z); x[5] = b2f(v.z >> 16);
        x[6] = b2f(v.w); x[7] = b2f(v.w >> 16);
        float ss = 0.f;
        #pragma unroll
        for (int t = 0; t < 8; ++t) ss += x[t] * x[t];
        ss += __shfl_xor(ss, 1); ss += __shfl_xor(ss, 2);
        ss += __shfl_xor(ss, 4); ss += __shfl_xor(ss, 8);
        float inv = rsqrtf(ss * (1.0f / 128.0f) + 1e-6f);
        float n[8];
        #pragma unroll
        for (int t = 0; t < 8; ++t) n[t] = x[t] * inv * w[l16 * 8 + t];
        float pr[8];
        #pragma unroll
        for (int t = 0; t < 8; ++t) pr[t] = __shfl_xor(n[t], 4);   // dims +-32
        if (l16 < 8) {
            #pragma unroll
            for (int t = 0; t < 8; ++t) {
                int dim = l16 * 8 + t;
                int i = dim & 31;
                float cs = tcs[i], sn = tsn[i];
                n[t] = (dim < 32) ? (n[t] * cs - pr[t] * sn) : (n[t] * cs + pr[t] * sn);
            }
        }
        uint4 o;
        o.x = f2b(n[0]) | (f2b(n[1]) << 16);
        o.y = f2b(n[2]) | (f2b(n[3]) << 16);
        o.z = f2b(n[4]) | (f2b(n[5]) << 16);
        o.w = f2b(n[6]) | (f2b(n[7]) << 16);
        *(uint4*)(row + l16 * 8) = o;
    }
}

// ============ pass 1: per-chunk KV outer product, frag-packed wbuf ============
__global__ __launch_bounds__(256) void chunk_kv(const unsigned short* __restrict__ qkv,
                                                unsigned short* __restrict__ wbuf)
{
    __shared__ unsigned short kt[128 * 72];   // kt[d][j]
    __shared__ unsigned short vt[128 * 72];   // vt[e][j] * kdec[j]
    __shared__ float kdec[64];
    int bi = blockIdx.x;
    int c = bi & 31, bh = bi >> 5, h = bh & 15, b = bh >> 4;
    int tid = threadIdx.x;
    float slope = -exp2f(-0.5f * (float)(h + 1)) * (1.0f + 1e-5f);

    if (tid < 64) kdec[tid] = expf(slope * (float)(63 - tid));
    __syncthreads();

    const unsigned short* kbase = qkv + ((size_t)(b * S_ + c * CHUNK_)) * NKV + HID + h * HD;
    const unsigned short* vbase = kbase + HID;

    for (int idx = tid; idx < 4096; idx += 256) {
        int j = idx >> 6, p = idx & 63;
        unsigned int ku = *(const unsigned int*)(kbase + (size_t)j * NKV + p * 2);
        kt[(2 * p) * 72 + j]     = (unsigned short)(ku & 0xffffu);
        kt[(2 * p + 1) * 72 + j] = (unsigned short)(ku >> 16);
        float kd = kdec[j];
        unsigned int vu = *(const unsigned int*)(vbase + (size_t)j * NKV + p * 2);
        vt[(2 * p) * 72 + j]     = (unsigned short)f2b(b2f(vu) * kd);
        vt[(2 * p + 1) * 72 + j] = (unsigned short)f2b(b2f(vu >> 16) * kd);
    }
    __syncthreads();

    int lane = tid & 63, wave = tid >> 6;
    int wm = (wave >> 1) * 64;     // e
    int wn = (wave & 1) * 64;      // d
    int l16 = lane & 15, quad = lane >> 4;

    f32x4 acc[4][4];
    #pragma unroll
    for (int i = 0; i < 4; ++i)
        #pragma unroll
        for (int j = 0; j < 4; ++j) { f32x4 z = {0.f,0.f,0.f,0.f}; acc[i][j] = z; }

    #pragma unroll
    for (int ks = 0; ks < 64; ks += 32) {
        bf16x8 af[4], bf[4];
        #pragma unroll
        for (int t = 0; t < 4; ++t) {
            af[t] = *(const bf16x8*)((const bf16_t*)vt + (wm + t * 16 + l16) * 72 + ks + quad * 8);
            bf[t] = *(const bf16x8*)((const bf16_t*)kt + (wn + t * 16 + l16) * 72 + ks + quad * 8);
        }
        #pragma unroll
        for (int mt = 0; mt < 4; ++mt)
            #pragma unroll
            for (int nt = 0; nt < 4; ++nt)
                acc[mt][nt] = __builtin_amdgcn_mfma_f32_16x16x32_bf16(af[mt], bf[nt], acc[mt][nt], 0, 0, 0);
    }

    // frag-packed write
    unsigned short* wp = wbuf + ((size_t)bi << 14);
    #pragma unroll
    for (int mt = 0; mt < 4; ++mt)
        #pragma unroll
        for (int nt = 0; nt < 4; ++nt) {
            int cid = ((wave >> 1) * 4 + mt) * 4 + (wave & 1) * 2 + (nt >> 1);
            int pos = ((nt & 1) * 2 + (l16 >> 3)) * 128 + (l16 & 7);
            #pragma unroll
            for (int r = 0; r < 4; ++r) {
                int e15 = quad * 4 + r;
                wp[cid * 512 + pos + e15 * 8] = (unsigned short)f2b(acc[mt][nt][r]);
            }
        }
}

// ============ pass 2: state scan, frag-packed, 512 blocks (2/CU for TLP) ======
__global__ __launch_bounds__(256) void state_scan(const unsigned short* __restrict__ wbuf,
                                                  const float* __restrict__ rs0,
                                                  unsigned short* __restrict__ stbuf)
{
    int bi = blockIdx.x;
    int s = bi & 15, bh = bi >> 4, h = bh & 15, b = bh >> 4;
    int tid = threadIdx.x;
    float slope = -exp2f(-0.5f * (float)(h + 1)) * (1.0f + 1e-5f);
    float lam = expf(slope * 64.0f);

    int T    = s * 256 + tid;          // 0..4095
    int cid  = T >> 7;
    int pos  = (T * 4) & 511;
    int a    = pos >> 7;               // (d>>3)&3
    int e15  = (pos >> 3) & 15;
    int d7   = pos & 7;                // 0 or 4
    int e    = (cid >> 2) * 16 + e15;
    int d0   = (cid & 3) * 32 + a * 8 + d7;

    float S[4];
    const float* rp = rs0 + ((size_t)(b * NH + h)) * HD * HD + e;
    #pragma unroll
    for (int t = 0; t < 4; ++t) S[t] = rp[(size_t)(d0 + t) * HD];

    size_t base = (((size_t)bh * NC) << 14) + (size_t)T * 4;
    uint2 w0 = *(const uint2*)(wbuf + base);
    uint2 w1 = *(const uint2*)(wbuf + base + (1 << 14));
    for (int c = 0; c < NC; ++c) {
        uint2 o;
        o.x = f2b(S[0]) | (f2b(S[1]) << 16);
        o.y = f2b(S[2]) | (f2b(S[3]) << 16);
        *(uint2*)(stbuf + base) = o;
        uint2 w2 = w1;
        if (c + 2 < NC) w2 = *(const uint2*)(wbuf + base + (2 << 14));
        S[0] = S[0] * lam + b2f(w0.x); S[1] = S[1] * lam + b2f(w0.x >> 16);
        S[2] = S[2] * lam + b2f(w0.y); S[3] = S[3] * lam + b2f(w0.y >> 16);
        w0 = w1; w1 = w2;
        base += (1 << 14);
    }
}

// ============ pass 3: per-chunk output  O = (mask.QK^T)@V + qdec*(Q@S_prev)
__global__ __launch_bounds__(256) void chunk_out(const unsigned short* __restrict__ qkv,
                                                 const unsigned short* __restrict__ stbuf,
                                                 unsigned short* __restrict__ obuf)
{
    __shared__ unsigned short qs[64 * 136];   // q[i][d]
    __shared__ unsigned short kss[64 * 136];  // k[j][d]
    __shared__ unsigned short vt[128 * 72];   // v^T[e][j]
    __shared__ unsigned short sc[64 * 72];    // masked scores [i][j]
    __shared__ float decp[65], decm[64];

    int bi = blockIdx.x;
    int c = bi & 31, bh = bi >> 5, h = bh & 15, b = bh >> 4;
    int tid = threadIdx.x;
    float slope = -exp2f(-0.5f * (float)(h + 1)) * (1.0f + 1e-5f);

    int lane = tid & 63, wave = tid >> 6;
    int l16 = lane & 15, quad = lane >> 4;
    int wn3 = wave * 32;

    if (tid < 65)       decp[tid]      = expf(slope * (float)tid);
    else if (tid < 129) decm[tid - 65] = expf(-slope * (float)(tid - 65));

    // prefetch st B-frags (frag-packed: contiguous 1KB per wave per frag)
    const unsigned short* stp = stbuf + (((size_t)bh * NC + c) << 14);
    bf16x8 bsf[4][2];
    #pragma unroll
    for (int ksp4 = 0; ksp4 < 4; ++ksp4)
        #pragma unroll
        for (int nt = 0; nt < 2; ++nt)
            bsf[ksp4][nt] = *(const bf16x8*)((const bf16_t*)stp +
                (((wave * 2 + nt) * 4 + ksp4) << 9) + lane * 8);

    const unsigned short* qrow = qkv + ((size_t)(b * S_ + c * CHUNK_)) * NKV + h * HD;
    const unsigned short* krow = qrow + HID;
    // stage q and k (rows of 128, padded stride 136), coalesced uint4
    for (int idx = tid; idx < 1024; idx += 256) {
        int row = idx >> 4, c8 = (idx & 15) * 8;
        *(uint4*)(qs  + row * 136 + c8) = *(const uint4*)(qrow + (size_t)row * NKV + c8);
        *(uint4*)(kss + row * 136 + c8) = *(const uint4*)(krow + (size_t)row * NKV + c8);
    }
    // stage v transposed
    const unsigned short* vbase = qrow + 2 * HID;
    for (int idx = tid; idx < 4096; idx += 256) {
        int j = idx >> 6, p = idx & 63;
        unsigned int vu = *(const unsigned int*)(vbase + (size_t)j * NKV + p * 2);
        vt[(2 * p) * 72 + j]     = (unsigned short)(vu & 0xffffu);
        vt[(2 * p + 1) * 72 + j] = (unsigned short)(vu >> 16);
    }
    __syncthreads();

    // scores
    {
        f32x4 accS[4];
        #pragma unroll
        for (int t = 0; t < 4; ++t) { f32x4 z = {0.f,0.f,0.f,0.f}; accS[t] = z; }
        #pragma unroll
        for (int ksp = 0; ksp < 128; ksp += 32) {
            bf16x8 aq = *(const bf16x8*)((const bf16_t*)qs + (wave * 16 + l16) * 136 + ksp + quad * 8);
            #pragma unroll
            for (int nt = 0; nt < 4; ++nt) {
                bf16x8 bk = *(const bf16x8*)((const bf16_t*)kss + (nt * 16 + l16) * 136 + ksp + quad * 8);
                accS[nt] = __builtin_amdgcn_mfma_f32_16x16x32_bf16(aq, bk, accS[nt], 0, 0, 0);
            }
        }
        float ad[4];
        #pragma unroll
        for (int r = 0; r < 4; ++r) ad[r] = decp[wave * 16 + quad * 4 + r];
        #pragma unroll
        for (int nt = 0; nt < 4; ++nt) {
            int j = nt * 16 + l16;
            float bd = decm[j];
            #pragma unroll
            for (int r = 0; r < 4; ++r) {
                int i = wave * 16 + quad * 4 + r;
                float v = (i >= j) ? accS[nt][r] * ad[r] * bd : 0.0f;
                sc[i * 72 + j] = (unsigned short)f2b(v);
            }
        }
    }
    __syncthreads();

    f32x4 accI[4][2], accE[4][2];
    #pragma unroll
    for (int i = 0; i < 4; ++i)
        #pragma unroll
        for (int j = 0; j < 2; ++j) { f32x4 z = {0.f,0.f,0.f,0.f}; accI[i][j] = z; accE[i][j] = z; }

    // intra: K = 64 (j)
    #pragma unroll
    for (int ksp = 0; ksp < 64; ksp += 32) {
        bf16x8 as[4], bv[2];
        #pragma unroll
        for (int mt = 0; mt < 4; ++mt)
            as[mt] = *(const bf16x8*)((const bf16_t*)sc + (mt * 16 + l16) * 72 + ksp + quad * 8);
        #pragma unroll
        for (int nt = 0; nt < 2; ++nt)
            bv[nt] = *(const bf16x8*)((const bf16_t*)vt + (wn3 + nt * 16 + l16) * 72 + ksp + quad * 8);
        #pragma unroll
        for (int mt = 0; mt < 4; ++mt)
            #pragma unroll
            for (int nt = 0; nt < 2; ++nt)
                accI[mt][nt] = __builtin_amdgcn_mfma_f32_16x16x32_bf16(as[mt], bv[nt], accI[mt][nt], 0, 0, 0);
    }
    // inter: K = 128 (d)
    #pragma unroll
    for (int ksp4 = 0; ksp4 < 4; ++ksp4) {
        bf16x8 aq[4];
        #pragma unroll
        for (int mt = 0; mt < 4; ++mt)
            aq[mt] = *(const bf16x8*)((const bf16_t*)qs + (mt * 16 + l16) * 136 + ksp4 * 32 + quad * 8);
        #pragma unroll
        for (int mt = 0; mt < 4; ++mt)
            #pragma unroll
            for (int nt = 0; nt < 2; ++nt)
                accE[mt][nt] = __builtin_amdgcn_mfma_f32_16x16x32_bf16(aq[mt], bsf[ksp4][nt], accE[mt][nt], 0, 0, 0);
    }

    // epilogue
    #pragma unroll
    for (int mt = 0; mt < 4; ++mt) {
        #pragma unroll
        for (int r = 0; r < 4; ++r) {
            int i = mt * 16 + quad * 4 + r;
            float qd = decp[i + 1];
            int orow = b * S_ + c * CHUNK_ + i;
            #pragma unroll
            for (int nt = 0; nt < 2; ++nt) {
                int col = h * HD + wn3 + nt * 16 + l16;
                float o = accI[mt][nt][r] + qd * accE[mt][nt][r];
                obuf[(size_t)orow * 2048 + col] = (unsigned short)f2b(o);
            }
        }
    }
}

// ------- group RMSNorm + sigmoid gate, vectorized x8: 1 block per row --------
__global__ __launch_bounds__(256) void gnorm_gate(const unsigned short* __restrict__ o,
                                                  unsigned short* __restrict__ gate,
                                                  const float* __restrict__ gw)
{
    int row = blockIdx.x;
    int tid = threadIdx.x;
    size_t base8 = (size_t)row * 256 + tid;
    uint4 ov = ((const uint4*)o)[base8];
    uint4 gv = ((const uint4*)gate)[base8];
    float x[8];
    x[0] = b2f(ov.x); x[1] = b2f(ov.x >> 16);
    x[2] = b2f(ov.y); x[3] = b2f(ov.y >> 16);
    x[4] = b2f(ov.z); x[5] = b2f(ov.z >> 16);
    x[6] = b2f(ov.w); x[7] = b2f(ov.w >> 16);
    float ss = 0.f;
    #pragma unroll
    for (int t = 0; t < 8; ++t) ss += x[t] * x[t];
    ss += __shfl_xor(ss, 1); ss += __shfl_xor(ss, 2); ss += __shfl_xor(ss, 4);
    ss += __shfl_xor(ss, 8); ss += __shfl_xor(ss, 16);
    float inv = rsqrtf(ss * (1.0f / 256.0f) + 1e-6f);
    const float4* gwp = (const float4*)(gw + tid * 8);
    float4 w0 = gwp[0], w1 = gwp[1];
    float g[8];
    g[0] = b2f(gv.x); g[1] = b2f(gv.x >> 16);
    g[2] = b2f(gv.y); g[3] = b2f(gv.y >> 16);
    g[4] = b2f(gv.z); g[5] = b2f(gv.z >> 16);
    g[6] = b2f(gv.w); g[7] = b2f(gv.w >> 16);
    float wv[8] = {w0.x, w0.y, w0.z, w0.w, w1.x, w1.y, w1.z, w1.w};
    float r[8];
    #pragma unroll
    for (int t = 0; t < 8; ++t) {
        float sig = 1.0f / (1.0f + expf(-g[t]));
        r[t] = x[t] * inv * wv[t] * sig;
    }
    uint4 out;
    out.x = f2b(r[0]) | (f2b(r[1]) << 16);
    out.y = f2b(r[2]) | (f2b(r[3]) << 16);
    out.z = f2b(r[4]) | (f2b(r[5]) << 16);
    out.w = f2b(r[6]) | (f2b(r[7]) << 16);
    ((uint4*)gate)[base8] = out;
}

// ---------------- launch ----------------
extern "C" void kernel_launch(void* const* d_in, const int* in_sizes, int n_in,
                              void* d_out, int out_size, void* d_ws, size_t ws_size,
                              hipStream_t stream) {
    const int*   positions = (const int*)d_in[0];
    const float* hidden    = (const float*)d_in[1];
    const float* rstate    = (const float*)d_in[2];
    const float* w_qkv     = (const float*)d_in[3];
    const float* w_g       = (const float*)d_in[4];
    const float* w_dense   = (const float*)d_in[5];
    const float* q_norm_w  = (const float*)d_in[6];
    const float* k_norm_w  = (const float*)d_in[7];
    const float* g_norm_w  = (const float*)d_in[8];
    float* out = (float*)d_out;

    const int MR = B_ * S_;  // 4096

    // ---- ws layout (unchanged) ----
    char* w = (char*)d_ws;
    unsigned short* qkv  = (unsigned short*)w;            w += (size_t)MR * NKV * 2;     // 50.3 MB
    unsigned short* gbuf = (unsigned short*)w;            w += (size_t)MR * 2048 * 2;    // 16.8 MB
    unsigned short* wdT  = (unsigned short*)w;            w += (size_t)HID * HID * 2;    // 8.4 MB
    char* regionA = w;                                    w += (size_t)MR * HID * 2 + (size_t)8192 * HID * 2; // 50.3 MB
    char* regionB = w;                                    // 33.6 MB
    unsigned short* hbf   = (unsigned short*)regionA;                                 // 16.8 MB
    unsigned short* btQG  = (unsigned short*)(regionA + (size_t)MR * HID * 2);        // [8192][2048] 33.5 MB
    unsigned short* stbuf = (unsigned short*)regionA;     // 32 MB, after GEMMs
    unsigned short* wbuf  = (unsigned short*)regionB;     // 32 MB
    unsigned short* obuf  = (unsigned short*)regionB;     // 16.8 MB, after pass2

    // ---- conversions (separate cvt + 32x32 transposes: round-10 proven) ----
    cvt_bf16<<<dim3((MR * HID / 8 + 255) / 256), dim3(256), 0, stream>>>(hidden, hbf, MR * HID / 8);
    transpose_qgd<<<dim3(64 * 320), dim3(256), 0, stream>>>(w_qkv, w_g, w_dense, btQG, wdT);

    // ---- fused qkv+gate projection: 256^2 barrier-light (512 wg x 512 thr) ----
    gemm_qg_256<<<dim3(512), dim3(512), 0, stream>>>(
        (const bf16_t*)hbf, (const bf16_t*)btQG, qkv, gbuf);
    // ---- q/k norm + rope (dedicated pass, LDS trig table) ----
    norm_rope<<<dim3(B_ * S_), dim3(256), 0, stream>>>(qkv, positions, q_norm_w, k_norm_w);

    // ---- attention: 3-pass chunked scan (frag-packed wbuf/stbuf) ----
    chunk_kv<<<dim3(B_ * NH * NC), dim3(256), 0, stream>>>(qkv, wbuf);
    state_scan<<<dim3(B_ * NH * 16), dim3(256), 0, stream>>>(wbuf, rstate, stbuf);
    chunk_out<<<dim3(B_ * NH * NC), dim3(256), 0, stream>>>(qkv, stbuf, obuf);

    // ---- group norm + gate (vectorized, 1 block/row) ----
    gnorm_gate<<<dim3(MR), dim3(256), 0, stream>>>(obuf, gbuf, g_norm_w);
    // ---- output projection (fp32 out), barrier-light 128^2 ----
    gemm_out_128<<<dim3(512), dim3(256), 0, stream>>>(
        (const bf16_t*)gbuf, (const bf16_t*)wdT, out);
}